// Round 3
// baseline (2293.889 us; speedup 1.0000x reference)
//
#include <hip/hip_runtime.h>

typedef unsigned short u16;
typedef __attribute__((ext_vector_type(8))) __bf16 bf16x8;
typedef __attribute__((ext_vector_type(4))) float floatx4;

#define NUM_LAYERS 4
#define STEPS 8
#define LRS 0.1f
#define M_ROWS 4096            // B*S
#define D_DIM 1024
#define V_DIM 32000
#define SM ((size_t)M_ROWS * D_DIM)      // elements per state buffer
#define WM ((size_t)D_DIM * D_DIM)       // elements per W

__device__ __forceinline__ u16 f2b(float f) {
    union { float f; unsigned u; } c; c.f = f;
    unsigned u = c.u;
    u = (u + 0x7FFFu + ((u >> 16) & 1u)) >> 16;   // RNE
    return (u16)u;
}
__device__ __forceinline__ float b2f(u16 b) {
    union { unsigned u; float f; } c; c.u = ((unsigned)b) << 16;
    return c.f;
}

// async 16B global -> LDS (wave-uniform LDS base + lane*16)
__device__ __forceinline__ void ld16(const u16* g, u16* l) {
    __builtin_amdgcn_global_load_lds(
        (const __attribute__((address_space(1))) void*)g,
        (__attribute__((address_space(3))) void*)l, 16, 0, 0);
}

// ---------------------------------------------------------------------------
// Shared GEMM core: C(128x128 f32 acc) = A(M x K bf16, row-major, lda=K)
//                                      @ B^T(N x K bf16, row-major, ldb=K)
// 256 threads = 4 waves in 2x2; each wave 64x64 = 4x4 frags of 16x16x32 MFMA.
// global_load_lds width=16 staging into stride-32 LDS with XOR chunk swizzle:
// LDS slot (row, c) holds global chunk c ^ ((row>>1)&3). Swizzle applied on
// the GLOBAL source address (DMA dest is lane-fixed); readers use
// qs = q ^ ((lr>>1)&3) -> quarter-wave bank touches are uniform 2-way (free).
// ---------------------------------------------------------------------------
__device__ __forceinline__ void gemm_core(const u16* __restrict__ A,
                                          const u16* __restrict__ B,
                                          int m0, int n0, int K,
                                          floatx4 (&acc)[4][4]) {
    __shared__ __align__(16) u16 a_lds[128 * 32];
    __shared__ __align__(16) u16 b_lds[128 * 32];
    const int tid  = threadIdx.x;
    const int lane = tid & 63;
    const int wave = tid >> 6;
    const int wm = wave >> 1, wn = wave & 1;
    const int q = lane >> 4, lr = lane & 15;
    const int qs = q ^ ((lr >> 1) & 3);          // read-side swizzle

    // staging map: LDS chunk C = sub*256 + wave*64 + lane -> row=C/4, c=C&3;
    // fetch global chunk c ^ ((row>>1)&3) = (lane&3) ^ ((lane>>3)&3)
    const int r0 = wave * 16 + (lane >> 2);
    const int cc = ((lane & 3) ^ ((lane >> 3) & 3)) * 8;
    const u16* ga0 = A + (size_t)(m0 + r0)      * K + cc;
    const u16* ga1 = A + (size_t)(m0 + r0 + 64) * K + cc;
    const u16* gb0 = B + (size_t)(n0 + r0)      * K + cc;
    const u16* gb1 = B + (size_t)(n0 + r0 + 64) * K + cc;
    u16* la0 = &a_lds[wave * 512];
    u16* la1 = &a_lds[2048 + wave * 512];
    u16* lb0 = &b_lds[wave * 512];
    u16* lb1 = &b_lds[2048 + wave * 512];

    #pragma unroll
    for (int i = 0; i < 4; i++)
        #pragma unroll
        for (int j = 0; j < 4; j++)
            acc[i][j] = floatx4{0.f, 0.f, 0.f, 0.f};

    for (int kt = 0; kt < K; kt += 32) {
        __syncthreads();                 // previous iter's LDS reads done
        ld16(ga0 + kt, la0);
        ld16(ga1 + kt, la1);
        ld16(gb0 + kt, lb0);
        ld16(gb1 + kt, lb1);
        __syncthreads();                 // drains vmcnt before reads
        bf16x8 af[4], bfv[4];
        #pragma unroll
        for (int mi = 0; mi < 4; mi++)
            af[mi] = *(const bf16x8*)&a_lds[(wm * 64 + mi * 16 + lr) * 32 + qs * 8];
        #pragma unroll
        for (int ni = 0; ni < 4; ni++)
            bfv[ni] = *(const bf16x8*)&b_lds[(wn * 64 + ni * 16 + lr) * 32 + qs * 8];
        #pragma unroll
        for (int mi = 0; mi < 4; mi++)
            #pragma unroll
            for (int ni = 0; ni < 4; ni++)
                acc[mi][ni] = __builtin_amdgcn_mfma_f32_16x16x32_bf16(
                    af[mi], bfv[ni], acc[mi][ni], 0, 0, 0);
    }
}

// eps_l = lower - b - mu_l @ W^T. If pc_accum==null: write eps as bf16.
// Else: skip the write, accumulate sum(eps^2) into *pc_accum (final pass).
__global__ __launch_bounds__(256) void eps_gemm_k(
        const u16* __restrict__ sbf, const u16* __restrict__ Wbf,
        const u16* __restrict__ xbf, const float* __restrict__ b_stack,
        u16* __restrict__ epsb, float* __restrict__ pc_accum) {
    const int z = blockIdx.z;
    const int m0 = blockIdx.y * 128, n0 = blockIdx.x * 128;
    floatx4 acc[4][4];
    gemm_core(sbf + (size_t)z * SM, Wbf + (size_t)z * WM, m0, n0, D_DIM, acc);
    const u16* lower = (z == 0) ? xbf : (sbf + (size_t)(z - 1) * SM);
    const float* bias = b_stack + z * D_DIM;
    u16* eo = epsb + (size_t)z * SM;
    const int tid = threadIdx.x, lane = tid & 63, wave = tid >> 6;
    const int wm = wave >> 1, wn = wave & 1, q = lane >> 4, lr = lane & 15;
    float sq = 0.f;
    #pragma unroll
    for (int mi = 0; mi < 4; mi++)
        #pragma unroll
        for (int ni = 0; ni < 4; ni++) {
            const int gcol = n0 + wn * 64 + ni * 16 + lr;
            const float bc = bias[gcol];
            #pragma unroll
            for (int r = 0; r < 4; r++) {
                const int grow = m0 + wm * 64 + mi * 16 + q * 4 + r;
                const size_t idx = (size_t)grow * D_DIM + gcol;
                const float e = b2f(lower[idx]) - bc - acc[mi][ni][r];
                if (pc_accum) sq += e * e;
                else          eo[idx] = f2b(e);
            }
        }
    if (pc_accum) {
        #pragma unroll
        for (int off = 1; off < 64; off <<= 1) sq += __shfl_xor(sq, off, 64);
        __shared__ float ls[4];
        if (lane == 0) ls[wave] = sq;
        __syncthreads();
        if (tid == 0) atomicAdd(pc_accum, ls[0] + ls[1] + ls[2] + ls[3]);
    }
}

// s_l += LR*(eps_l @ W) - LR*eps_{l+1};  states live as bf16 only
__global__ __launch_bounds__(256) void upd_gemm_k(
        const u16* __restrict__ epsb, const u16* __restrict__ WTbf,
        u16* __restrict__ sbf) {
    const int z = blockIdx.z;
    const int m0 = blockIdx.y * 128, n0 = blockIdx.x * 128;
    floatx4 acc[4][4];
    gemm_core(epsb + (size_t)z * SM, WTbf + (size_t)z * WM, m0, n0, D_DIM, acc);
    u16* Sb = sbf + (size_t)z * SM;
    const bool hn = (z < 3);
    const u16* en = epsb + (size_t)(hn ? (z + 1) : z) * SM;
    const int tid = threadIdx.x, lane = tid & 63, wave = tid >> 6;
    const int wm = wave >> 1, wn = wave & 1, q = lane >> 4, lr = lane & 15;
    #pragma unroll
    for (int mi = 0; mi < 4; mi++)
        #pragma unroll
        for (int ni = 0; ni < 4; ni++) {
            const int gcol = n0 + wn * 64 + ni * 16 + lr;
            #pragma unroll
            for (int r = 0; r < 4; r++) {
                const int grow = m0 + wm * 64 + mi * 16 + q * 4 + r;
                const size_t idx = (size_t)grow * D_DIM + gcol;
                float v = b2f(Sb[idx]) + LRS * acc[mi][ni][r];
                if (hn) v -= LRS * b2f(en[idx]);
                Sb[idx] = f2b(v);
            }
        }
}

// logits tile + fused online-softmax partials + target-logit capture
// grid: x = m-tile (32, fastest) so co-resident blocks share one B n-strip
__global__ __launch_bounds__(256) void logits_k(
        const u16* __restrict__ s4bf, const u16* __restrict__ oWb,
        const float* __restrict__ out_b, const int* __restrict__ targets,
        float* __restrict__ part_m, float* __restrict__ part_s,
        float* __restrict__ tlog) {
    const int m0 = blockIdx.x * 128, n0 = blockIdx.y * 128;
    floatx4 acc[4][4];
    gemm_core(s4bf, oWb, m0, n0, D_DIM, acc);
    __shared__ float redm[128][2];
    __shared__ float reds[128][2];
    const int tid = threadIdx.x, lane = tid & 63, wave = tid >> 6;
    const int wm = wave >> 1, wn = wave & 1, q = lane >> 4, lr = lane & 15;
    float ob[4];
    #pragma unroll
    for (int ni = 0; ni < 4; ni++) ob[ni] = out_b[n0 + wn * 64 + ni * 16 + lr];
    #pragma unroll
    for (int mi = 0; mi < 4; mi++) {
        #pragma unroll
        for (int r = 0; r < 4; r++) {
            const int grow = m0 + wm * 64 + mi * 16 + q * 4 + r;
            float l[4];
            #pragma unroll
            for (int ni = 0; ni < 4; ni++) l[ni] = acc[mi][ni][r] + ob[ni];
            if ((grow & 511) != 511) {           // valid row (s < 511)
                const int t = targets[grow + 1];
                #pragma unroll
                for (int ni = 0; ni < 4; ni++) {
                    const int gcol = n0 + wn * 64 + ni * 16 + lr;
                    if (t == gcol) tlog[grow] = l[ni];
                }
            }
            float mx = fmaxf(fmaxf(l[0], l[1]), fmaxf(l[2], l[3]));
            #pragma unroll
            for (int off = 1; off < 16; off <<= 1)
                mx = fmaxf(mx, __shfl_xor(mx, off, 64));
            float sm = __expf(l[0] - mx) + __expf(l[1] - mx) +
                       __expf(l[2] - mx) + __expf(l[3] - mx);
            #pragma unroll
            for (int off = 1; off < 16; off <<= 1)
                sm += __shfl_xor(sm, off, 64);
            if (lr == 0) {
                const int rrow = wm * 64 + mi * 16 + q * 4 + r;
                redm[rrow][wn] = mx;
                reds[rrow][wn] = sm;
            }
        }
    }
    __syncthreads();
    if (tid < 128) {
        float ma = redm[tid][0], mb = redm[tid][1];
        float M = fmaxf(ma, mb);
        float S = reds[tid][0] * __expf(ma - M) + reds[tid][1] * __expf(mb - M);
        part_m[(size_t)blockIdx.y * M_ROWS + m0 + tid] = M;
        part_s[(size_t)blockIdx.y * M_ROWS + m0 + tid] = S;
    }
}

__device__ __forceinline__ unsigned pk2(float a, float b) {
    return (unsigned)f2b(a) | ((unsigned)f2b(b) << 16);
}

__global__ void gather_k(const int* __restrict__ ids,
                         const float* __restrict__ emb,
                         u16* __restrict__ xbf) {
    const int row = blockIdx.x;
    const int c = threadIdx.x * 4;
    float4 v = *(const float4*)(emb + (size_t)ids[row] * D_DIM + c);
    uint2 o; o.x = pk2(v.x, v.y); o.y = pk2(v.z, v.w);
    *(uint2*)(xbf + (size_t)row * D_DIM + c) = o;
}

__global__ void conv_w_k(const float* __restrict__ W,
                         u16* __restrict__ Wbf, u16* __restrict__ WTbf) {
    __shared__ float t[32][33];
    const int z = blockIdx.z;
    const int i = blockIdx.y * 32 + threadIdx.y;
    const int j = blockIdx.x * 32 + threadIdx.x;
    const float v = W[(size_t)z * WM + (size_t)i * D_DIM + j];
    Wbf[(size_t)z * WM + (size_t)i * D_DIM + j] = f2b(v);
    t[threadIdx.y][threadIdx.x] = v;
    __syncthreads();
    const int jo = blockIdx.x * 32 + threadIdx.y;
    const int io = blockIdx.y * 32 + threadIdx.x;
    WTbf[(size_t)z * WM + (size_t)jo * D_DIM + io] = f2b(t[threadIdx.x][threadIdx.y]);
}

__global__ void conv_outw_k(const float* __restrict__ oW, u16* __restrict__ oWb) {
    const size_t i = ((size_t)blockIdx.x * 256 + threadIdx.x) * 4;
    float4 v = *(const float4*)(oW + i);
    uint2 o; o.x = pk2(v.x, v.y); o.y = pk2(v.z, v.w);
    *(uint2*)(oWb + i) = o;
}

__global__ void init_states_k(const float* __restrict__ si,
                              u16* __restrict__ sbf) {
    const size_t i = ((size_t)blockIdx.x * 256 + threadIdx.x) * 4;
    float4 v = *(const float4*)(si + i);
    uint2 o; o.x = pk2(v.x, v.y); o.y = pk2(v.z, v.w);
    *(uint2*)(sbf + i) = o;
}

__global__ void ce_reduce_k(const float* __restrict__ part_m,
                            const float* __restrict__ part_s,
                            const float* __restrict__ tlog,
                            float* __restrict__ ce_sum) {
    const int row = blockIdx.x;
    if ((row & 511) == 511) return;
    const int tid = threadIdx.x;
    const int NT = V_DIM / 128;  // 250
    float m = -3.0e38f;
    for (int nt = tid; nt < NT; nt += 256)
        m = fmaxf(m, part_m[(size_t)nt * M_ROWS + row]);
    #pragma unroll
    for (int off = 1; off < 64; off <<= 1) m = fmaxf(m, __shfl_xor(m, off, 64));
    __shared__ float sm[4], ss[4];
    if ((tid & 63) == 0) sm[tid >> 6] = m;
    __syncthreads();
    m = fmaxf(fmaxf(sm[0], sm[1]), fmaxf(sm[2], sm[3]));
    float s = 0.f;
    for (int nt = tid; nt < NT; nt += 256)
        s += part_s[(size_t)nt * M_ROWS + row] *
             __expf(part_m[(size_t)nt * M_ROWS + row] - m);
    #pragma unroll
    for (int off = 1; off < 64; off <<= 1) s += __shfl_xor(s, off, 64);
    if ((tid & 63) == 0) ss[tid >> 6] = s;
    __syncthreads();
    if (tid == 0) {
        float loss = m + __logf(ss[0] + ss[1] + ss[2] + ss[3]) - tlog[row];
        atomicAdd(ce_sum, loss);
    }
}

__global__ void finalize_k(const float* __restrict__ scal, float* __restrict__ out) {
    out[0] = scal[0] / 4088.0f;
    out[1] = scal[1] / (float)(4 * SM);
}

extern "C" void kernel_launch(void* const* d_in, const int* in_sizes, int n_in,
                              void* d_out, int out_size, void* d_ws, size_t ws_size,
                              hipStream_t stream) {
    (void)in_sizes; (void)n_in; (void)out_size; (void)ws_size;
    const int*   ids = (const int*)d_in[0];
    const int*   tgt = (const int*)d_in[1];
    const float* emb = (const float*)d_in[2];
    const float* W   = (const float*)d_in[3];
    const float* bs  = (const float*)d_in[4];
    const float* oW  = (const float*)d_in[5];
    const float* ob  = (const float*)d_in[6];
    const float* si  = (const float*)d_in[7];

    char* ws = (char*)d_ws;
    u16*   sbf    = (u16*)  (ws + 0);             // 33,554,432 B
    u16*   epsb   = (u16*)  (ws + 33554432);      // 33,554,432 B
    u16*   xbf    = (u16*)  (ws + 67108864);      //  8,388,608 B
    u16*   Wbf    = (u16*)  (ws + 75497472);      //  8,388,608 B
    u16*   WTbf   = (u16*)  (ws + 83886080);      //  8,388,608 B
    u16*   oWb    = (u16*)  (ws + 92274688);      // 65,536,000 B
    float* part_m = (float*)(ws + 157810688);     //  4,096,000 B
    float* part_s = (float*)(ws + 161906688);     //  4,096,000 B
    float* tlog   = (float*)(ws + 166002688);     //     16,384 B
    float* scal   = (float*)(ws + 166019072);     //        256 B

    hipMemsetAsync(scal, 0, 256, stream);
    gather_k<<<M_ROWS, 256, 0, stream>>>(ids, emb, xbf);
    conv_w_k<<<dim3(32, 32, 4), dim3(32, 32), 0, stream>>>(W, Wbf, WTbf);
    conv_outw_k<<<(V_DIM * D_DIM) / 1024, 256, 0, stream>>>(oW, oWb);
    init_states_k<<<(4 * (int)SM) / 1024, 256, 0, stream>>>(si, sbf);

    for (int step = 0; step < STEPS; ++step) {
        eps_gemm_k<<<dim3(8, 32, 4), 256, 0, stream>>>(sbf, Wbf, xbf, bs, epsb,
                                                       nullptr);
        upd_gemm_k<<<dim3(8, 32, 4), 256, 0, stream>>>(epsb, WTbf, sbf);
    }
    // final eps pass: no eps write, accumulate sum(eps^2) directly
    eps_gemm_k<<<dim3(8, 32, 4), 256, 0, stream>>>(sbf, Wbf, xbf, bs, epsb,
                                                   scal + 1);
    logits_k<<<dim3(32, V_DIM / 128), 256, 0, stream>>>(sbf + 3 * SM, oWb, ob, tgt,
                                                        part_m, part_s, tlog);
    ce_reduce_k<<<M_ROWS, 256, 0, stream>>>(part_m, part_s, tlog, scal);
    finalize_k<<<1, 1, 0, stream>>>(scal, (float*)d_out);
}

// Round 4
// 1864.406 us; speedup vs baseline: 1.2304x; 1.2304x over previous
//
#include <hip/hip_runtime.h>

typedef unsigned short u16;
typedef __attribute__((ext_vector_type(8))) __bf16 bf16x8;
typedef __attribute__((ext_vector_type(4))) float floatx4;

#define NUM_LAYERS 4
#define STEPS 8
#define LRS 0.1f
#define M_ROWS 4096            // B*S
#define D_DIM 1024
#define V_DIM 32000
#define SM ((size_t)M_ROWS * D_DIM)      // elements per state buffer
#define WM ((size_t)D_DIM * D_DIM)       // elements per W

__device__ __forceinline__ u16 f2b(float f) {
    union { float f; unsigned u; } c; c.f = f;
    unsigned u = c.u;
    u = (u + 0x7FFFu + ((u >> 16) & 1u)) >> 16;   // RNE
    return (u16)u;
}
__device__ __forceinline__ float b2f(u16 b) {
    union { unsigned u; float f; } c; c.u = ((unsigned)b) << 16;
    return c.f;
}
__device__ __forceinline__ unsigned pk2(float a, float b) {
    return (unsigned)f2b(a) | ((unsigned)f2b(b) << 16);
}

// async 16B global -> LDS (wave-uniform LDS base + lane*16)
__device__ __forceinline__ void ld16(const u16* g, u16* l) {
    __builtin_amdgcn_global_load_lds(
        (const __attribute__((address_space(1))) void*)g,
        (__attribute__((address_space(3))) void*)l, 16, 0, 0);
}

// ---------------------------------------------------------------------------
// Shared GEMM core: C(128x128 f32 acc) = A(M x K bf16, row-major, lda=K)
//                                      @ B^T(N x K bf16, row-major, ldb=K)
// 256 threads = 4 waves in 2x2; each wave 64x64 = 4x4 frags of 16x16x32 MFMA.
// global_load_lds width=16 staging into stride-32 LDS with XOR chunk swizzle
// (conflict-free, verified R3: SQ_LDS_BANK_CONFLICT == 0).
// smem: caller-provided 8192 u16 (a tile = [0,4096), b tile = [4096,8192)).
// ---------------------------------------------------------------------------
__device__ __forceinline__ void gemm_core(const u16* __restrict__ A,
                                          const u16* __restrict__ B,
                                          int m0, int n0, int K,
                                          floatx4 (&acc)[4][4],
                                          u16* smem) {
    u16* a_lds = smem;
    u16* b_lds = smem + 4096;
    const int tid  = threadIdx.x;
    const int lane = tid & 63;
    const int wave = tid >> 6;
    const int wm = wave >> 1, wn = wave & 1;
    const int q = lane >> 4, lr = lane & 15;
    const int qs = q ^ ((lr >> 1) & 3);          // read-side swizzle

    const int r0 = wave * 16 + (lane >> 2);
    const int cc = ((lane & 3) ^ ((lane >> 3) & 3)) * 8;
    const u16* ga0 = A + (size_t)(m0 + r0)      * K + cc;
    const u16* ga1 = A + (size_t)(m0 + r0 + 64) * K + cc;
    const u16* gb0 = B + (size_t)(n0 + r0)      * K + cc;
    const u16* gb1 = B + (size_t)(n0 + r0 + 64) * K + cc;
    u16* la0 = &a_lds[wave * 512];
    u16* la1 = &a_lds[2048 + wave * 512];
    u16* lb0 = &b_lds[wave * 512];
    u16* lb1 = &b_lds[2048 + wave * 512];

    #pragma unroll
    for (int i = 0; i < 4; i++)
        #pragma unroll
        for (int j = 0; j < 4; j++)
            acc[i][j] = floatx4{0.f, 0.f, 0.f, 0.f};

    for (int kt = 0; kt < K; kt += 32) {
        __syncthreads();                 // previous iter's LDS reads done
        ld16(ga0 + kt, la0);
        ld16(ga1 + kt, la1);
        ld16(gb0 + kt, lb0);
        ld16(gb1 + kt, lb1);
        __syncthreads();                 // drains vmcnt before reads
        bf16x8 af[4], bfv[4];
        #pragma unroll
        for (int mi = 0; mi < 4; mi++)
            af[mi] = *(const bf16x8*)&a_lds[(wm * 64 + mi * 16 + lr) * 32 + qs * 8];
        #pragma unroll
        for (int ni = 0; ni < 4; ni++)
            bfv[ni] = *(const bf16x8*)&b_lds[(wn * 64 + ni * 16 + lr) * 32 + qs * 8];
        #pragma unroll
        for (int mi = 0; mi < 4; mi++)
            #pragma unroll
            for (int ni = 0; ni < 4; ni++)
                acc[mi][ni] = __builtin_amdgcn_mfma_f32_16x16x32_bf16(
                    af[mi], bfv[ni], acc[mi][ni], 0, 0, 0);
    }
}

// Epilogue staging map (32 rows x 128 cols bf16 per pass, 8KB in smem[0..4095]):
//   slot row  = wm*16 + q*4 + r  (global row = m0 + (row>>4)*64 + mi*16 + (row&15))
//   col chunk rotation: slot_chunk = (chunk + 4*((row>>2)&3)) & 15  -> both LDS
//   phases uniform 2-way bank touches (free).

// eps_l = lower - b - mu_l @ W^T. If pc_accum==null: write eps as bf16 (16B
// coalesced). Else: skip the write, accumulate sum(eps^2) into *pc_accum.
__global__ __launch_bounds__(256) void eps_gemm_k(
        const u16* __restrict__ sbf, const u16* __restrict__ Wbf,
        const u16* __restrict__ xbf, const float* __restrict__ b_stack,
        u16* __restrict__ epsb, float* __restrict__ pc_accum) {
    __shared__ __align__(16) u16 smem[8192];
    const int z = blockIdx.z;
    const int m0 = blockIdx.y * 128, n0 = blockIdx.x * 128;
    floatx4 acc[4][4];
    gemm_core(sbf + (size_t)z * SM, Wbf + (size_t)z * WM, m0, n0, D_DIM, acc, smem);
    const u16* lower = (z == 0) ? xbf : (sbf + (size_t)(z - 1) * SM);
    const float* bias = b_stack + z * D_DIM;
    u16* eo = epsb + (size_t)z * SM;
    const int tid = threadIdx.x, lane = tid & 63, wave = tid >> 6;
    const int wm = wave >> 1, wn = wave & 1, q = lane >> 4, lr = lane & 15;
    float sq = 0.f;
    #pragma unroll
    for (int mi = 0; mi < 4; mi++) {
        __syncthreads();
        #pragma unroll
        for (int ni = 0; ni < 4; ni++) {
            const int col = wn * 64 + ni * 16 + lr;
            const float bc = bias[n0 + col];
            #pragma unroll
            for (int r = 0; r < 4; r++) {
                const int row = wm * 16 + q * 4 + r;
                const int scn = ((col >> 3) + ((row >> 2) & 3) * 4) & 15;
                smem[row * 128 + scn * 8 + (col & 7)] = f2b(acc[mi][ni][r] + bc);
            }
        }
        __syncthreads();
        #pragma unroll
        for (int h = 0; h < 2; h++) {
            const int c = tid + h * 256;
            const int lrow = c >> 4, ch = c & 15;
            const int scn = (ch + ((lrow >> 2) & 3) * 4) & 15;
            const int grow = m0 + (lrow >> 4) * 64 + mi * 16 + (lrow & 15);
            const size_t gidx = (size_t)grow * D_DIM + n0 + ch * 8;
            bf16x8 st = *(const bf16x8*)&smem[lrow * 128 + scn * 8];
            bf16x8 lo = *(const bf16x8*)(lower + gidx);
            float e[8];
            #pragma unroll
            for (int i = 0; i < 8; i++) e[i] = (float)lo[i] - (float)st[i];
            if (pc_accum) {
                #pragma unroll
                for (int i = 0; i < 8; i++) sq += e[i] * e[i];
            } else {
                uint4 ov;
                ov.x = pk2(e[0], e[1]); ov.y = pk2(e[2], e[3]);
                ov.z = pk2(e[4], e[5]); ov.w = pk2(e[6], e[7]);
                *(uint4*)(eo + gidx) = ov;
            }
        }
    }
    if (pc_accum) {
        #pragma unroll
        for (int off = 1; off < 64; off <<= 1) sq += __shfl_xor(sq, off, 64);
        __shared__ float ls[4];
        if (lane == 0) ls[wave] = sq;
        __syncthreads();
        if (tid == 0) atomicAdd(pc_accum, ls[0] + ls[1] + ls[2] + ls[3]);
    }
}

// s_l += LR*(eps_l @ W) - LR*eps_{l+1};  states live as bf16 only
__global__ __launch_bounds__(256) void upd_gemm_k(
        const u16* __restrict__ epsb, const u16* __restrict__ WTbf,
        u16* __restrict__ sbf) {
    __shared__ __align__(16) u16 smem[8192];
    const int z = blockIdx.z;
    const int m0 = blockIdx.y * 128, n0 = blockIdx.x * 128;
    floatx4 acc[4][4];
    gemm_core(epsb + (size_t)z * SM, WTbf + (size_t)z * WM, m0, n0, D_DIM, acc, smem);
    u16* Sb = sbf + (size_t)z * SM;
    const bool hn = (z < 3);
    const u16* en = epsb + (size_t)(hn ? (z + 1) : z) * SM;
    const int tid = threadIdx.x, lane = tid & 63, wave = tid >> 6;
    const int wm = wave >> 1, wn = wave & 1, q = lane >> 4, lr = lane & 15;
    #pragma unroll
    for (int mi = 0; mi < 4; mi++) {
        __syncthreads();
        #pragma unroll
        for (int ni = 0; ni < 4; ni++) {
            const int col = wn * 64 + ni * 16 + lr;
            #pragma unroll
            for (int r = 0; r < 4; r++) {
                const int row = wm * 16 + q * 4 + r;
                const int scn = ((col >> 3) + ((row >> 2) & 3) * 4) & 15;
                smem[row * 128 + scn * 8 + (col & 7)] = f2b(LRS * acc[mi][ni][r]);
            }
        }
        __syncthreads();
        #pragma unroll
        for (int h = 0; h < 2; h++) {
            const int c = tid + h * 256;
            const int lrow = c >> 4, ch = c & 15;
            const int scn = (ch + ((lrow >> 2) & 3) * 4) & 15;
            const int grow = m0 + (lrow >> 4) * 64 + mi * 16 + (lrow & 15);
            const size_t gidx = (size_t)grow * D_DIM + n0 + ch * 8;
            bf16x8 st = *(const bf16x8*)&smem[lrow * 128 + scn * 8];
            bf16x8 S8 = *(const bf16x8*)(Sb + gidx);
            float v[8];
            #pragma unroll
            for (int i = 0; i < 8; i++) v[i] = (float)S8[i] + (float)st[i];
            if (hn) {
                bf16x8 e8 = *(const bf16x8*)(en + gidx);
                #pragma unroll
                for (int i = 0; i < 8; i++) v[i] -= LRS * (float)e8[i];
            }
            uint4 ov;
            ov.x = pk2(v[0], v[1]); ov.y = pk2(v[2], v[3]);
            ov.z = pk2(v[4], v[5]); ov.w = pk2(v[6], v[7]);
            *(uint4*)(Sb + gidx) = ov;
        }
    }
}

// logits tile + fused online-softmax partials + target-logit capture
// grid: x = m-tile (32, fastest) so co-resident blocks share one B n-strip
__global__ __launch_bounds__(256) void logits_k(
        const u16* __restrict__ s4bf, const u16* __restrict__ oWb,
        const float* __restrict__ out_b, const int* __restrict__ targets,
        float* __restrict__ part_m, float* __restrict__ part_s,
        float* __restrict__ tlog) {
    __shared__ __align__(16) u16 smem[8192];
    const int m0 = blockIdx.x * 128, n0 = blockIdx.y * 128;
    floatx4 acc[4][4];
    gemm_core(s4bf, oWb, m0, n0, D_DIM, acc, smem);
    __shared__ float redm[128][2];
    __shared__ float reds[128][2];
    const int tid = threadIdx.x, lane = tid & 63, wave = tid >> 6;
    const int wm = wave >> 1, wn = wave & 1, q = lane >> 4, lr = lane & 15;
    float ob[4];
    #pragma unroll
    for (int ni = 0; ni < 4; ni++) ob[ni] = out_b[n0 + wn * 64 + ni * 16 + lr];
    #pragma unroll
    for (int mi = 0; mi < 4; mi++) {
        #pragma unroll
        for (int r = 0; r < 4; r++) {
            const int grow = m0 + wm * 64 + mi * 16 + q * 4 + r;
            float l[4];
            #pragma unroll
            for (int ni = 0; ni < 4; ni++) l[ni] = acc[mi][ni][r] + ob[ni];
            if ((grow & 511) != 511) {           // valid row (s < 511)
                const int t = targets[grow + 1];
                #pragma unroll
                for (int ni = 0; ni < 4; ni++) {
                    const int gcol = n0 + wn * 64 + ni * 16 + lr;
                    if (t == gcol) tlog[grow] = l[ni];
                }
            }
            float mx = fmaxf(fmaxf(l[0], l[1]), fmaxf(l[2], l[3]));
            #pragma unroll
            for (int off = 1; off < 16; off <<= 1)
                mx = fmaxf(mx, __shfl_xor(mx, off, 64));
            float sm = __expf(l[0] - mx) + __expf(l[1] - mx) +
                       __expf(l[2] - mx) + __expf(l[3] - mx);
            #pragma unroll
            for (int off = 1; off < 16; off <<= 1)
                sm += __shfl_xor(sm, off, 64);
            if (lr == 0) {
                const int rrow = wm * 64 + mi * 16 + q * 4 + r;
                redm[rrow][wn] = mx;
                reds[rrow][wn] = sm;
            }
        }
    }
    __syncthreads();
    if (tid < 128) {
        float ma = redm[tid][0], mb = redm[tid][1];
        float M = fmaxf(ma, mb);
        float S = reds[tid][0] * __expf(ma - M) + reds[tid][1] * __expf(mb - M);
        part_m[(size_t)blockIdx.y * M_ROWS + m0 + tid] = M;
        part_s[(size_t)blockIdx.y * M_ROWS + m0 + tid] = S;
    }
}

__global__ void gather_k(const int* __restrict__ ids,
                         const float* __restrict__ emb,
                         u16* __restrict__ xbf) {
    const int row = blockIdx.x;
    const int c = threadIdx.x * 4;
    float4 v = *(const float4*)(emb + (size_t)ids[row] * D_DIM + c);
    uint2 o; o.x = pk2(v.x, v.y); o.y = pk2(v.z, v.w);
    *(uint2*)(xbf + (size_t)row * D_DIM + c) = o;
}

__global__ void conv_w_k(const float* __restrict__ W,
                         u16* __restrict__ Wbf, u16* __restrict__ WTbf) {
    __shared__ float t[32][33];
    const int z = blockIdx.z;
    const int i = blockIdx.y * 32 + threadIdx.y;
    const int j = blockIdx.x * 32 + threadIdx.x;
    const float v = W[(size_t)z * WM + (size_t)i * D_DIM + j];
    Wbf[(size_t)z * WM + (size_t)i * D_DIM + j] = f2b(v);
    t[threadIdx.y][threadIdx.x] = v;
    __syncthreads();
    const int jo = blockIdx.x * 32 + threadIdx.y;
    const int io = blockIdx.y * 32 + threadIdx.x;
    WTbf[(size_t)z * WM + (size_t)jo * D_DIM + io] = f2b(t[threadIdx.x][threadIdx.y]);
}

__global__ void conv_outw_k(const float* __restrict__ oW, u16* __restrict__ oWb) {
    const size_t i = ((size_t)blockIdx.x * 256 + threadIdx.x) * 4;
    float4 v = *(const float4*)(oW + i);
    uint2 o; o.x = pk2(v.x, v.y); o.y = pk2(v.z, v.w);
    *(uint2*)(oWb + i) = o;
}

__global__ void init_states_k(const float* __restrict__ si,
                              u16* __restrict__ sbf) {
    const size_t i = ((size_t)blockIdx.x * 256 + threadIdx.x) * 4;
    float4 v = *(const float4*)(si + i);
    uint2 o; o.x = pk2(v.x, v.y); o.y = pk2(v.z, v.w);
    *(uint2*)(sbf + i) = o;
}

__global__ void ce_reduce_k(const float* __restrict__ part_m,
                            const float* __restrict__ part_s,
                            const float* __restrict__ tlog,
                            float* __restrict__ ce_sum) {
    const int row = blockIdx.x;
    if ((row & 511) == 511) return;
    const int tid = threadIdx.x;
    const int NT = V_DIM / 128;  // 250
    float m = -3.0e38f;
    for (int nt = tid; nt < NT; nt += 256)
        m = fmaxf(m, part_m[(size_t)nt * M_ROWS + row]);
    #pragma unroll
    for (int off = 1; off < 64; off <<= 1) m = fmaxf(m, __shfl_xor(m, off, 64));
    __shared__ float sm[4], ss[4];
    if ((tid & 63) == 0) sm[tid >> 6] = m;
    __syncthreads();
    m = fmaxf(fmaxf(sm[0], sm[1]), fmaxf(sm[2], sm[3]));
    float s = 0.f;
    for (int nt = tid; nt < NT; nt += 256)
        s += part_s[(size_t)nt * M_ROWS + row] *
             __expf(part_m[(size_t)nt * M_ROWS + row] - m);
    #pragma unroll
    for (int off = 1; off < 64; off <<= 1) s += __shfl_xor(s, off, 64);
    if ((tid & 63) == 0) ss[tid >> 6] = s;
    __syncthreads();
    if (tid == 0) {
        float loss = m + __logf(ss[0] + ss[1] + ss[2] + ss[3]) - tlog[row];
        atomicAdd(ce_sum, loss);
    }
}

__global__ void finalize_k(const float* __restrict__ scal, float* __restrict__ out) {
    out[0] = scal[0] / 4088.0f;
    out[1] = scal[1] / (float)(4 * SM);
}

extern "C" void kernel_launch(void* const* d_in, const int* in_sizes, int n_in,
                              void* d_out, int out_size, void* d_ws, size_t ws_size,
                              hipStream_t stream) {
    (void)in_sizes; (void)n_in; (void)out_size; (void)ws_size;
    const int*   ids = (const int*)d_in[0];
    const int*   tgt = (const int*)d_in[1];
    const float* emb = (const float*)d_in[2];
    const float* W   = (const float*)d_in[3];
    const float* bs  = (const float*)d_in[4];
    const float* oW  = (const float*)d_in[5];
    const float* ob  = (const float*)d_in[6];
    const float* si  = (const float*)d_in[7];

    char* ws = (char*)d_ws;
    u16*   sbf    = (u16*)  (ws + 0);             // 33,554,432 B
    u16*   epsb   = (u16*)  (ws + 33554432);      // 33,554,432 B
    u16*   xbf    = (u16*)  (ws + 67108864);      //  8,388,608 B
    u16*   Wbf    = (u16*)  (ws + 75497472);      //  8,388,608 B
    u16*   WTbf   = (u16*)  (ws + 83886080);      //  8,388,608 B
    u16*   oWb    = (u16*)  (ws + 92274688);      // 65,536,000 B
    float* part_m = (float*)(ws + 157810688);     //  4,096,000 B
    float* part_s = (float*)(ws + 161906688);     //  4,096,000 B
    float* tlog   = (float*)(ws + 166002688);     //     16,384 B
    float* scal   = (float*)(ws + 166019072);     //        256 B

    hipMemsetAsync(scal, 0, 256, stream);
    gather_k<<<M_ROWS, 256, 0, stream>>>(ids, emb, xbf);
    conv_w_k<<<dim3(32, 32, 4), dim3(32, 32), 0, stream>>>(W, Wbf, WTbf);
    conv_outw_k<<<(V_DIM * D_DIM) / 1024, 256, 0, stream>>>(oW, oWb);
    init_states_k<<<(4 * (int)SM) / 1024, 256, 0, stream>>>(si, sbf);

    for (int step = 0; step < STEPS; ++step) {
        eps_gemm_k<<<dim3(8, 32, 4), 256, 0, stream>>>(sbf, Wbf, xbf, bs, epsb,
                                                       nullptr);
        upd_gemm_k<<<dim3(8, 32, 4), 256, 0, stream>>>(epsb, WTbf, sbf);
    }
    // final eps pass: no eps write, accumulate sum(eps^2) directly
    eps_gemm_k<<<dim3(8, 32, 4), 256, 0, stream>>>(sbf, Wbf, xbf, bs, epsb,
                                                   scal + 1);
    logits_k<<<dim3(32, V_DIM / 128), 256, 0, stream>>>(sbf + 3 * SM, oWb, ob, tgt,
                                                        part_m, part_s, tlog);
    ce_reduce_k<<<M_ROWS, 256, 0, stream>>>(part_m, part_s, tlog, scal);
    finalize_k<<<1, 1, 0, stream>>>(scal, (float*)d_out);
}

// Round 5
// 1641.421 us; speedup vs baseline: 1.3975x; 1.1358x over previous
//
#include <hip/hip_runtime.h>

typedef unsigned short u16;
typedef __attribute__((ext_vector_type(8))) __bf16 bf16x8;
typedef __attribute__((ext_vector_type(4))) float floatx4;

#define NUM_LAYERS 4
#define STEPS 8
#define LRS 0.1f
#define M_ROWS 4096            // B*S
#define D_DIM 1024
#define V_DIM 32000
#define KDIM 1024              // GEMM K (compile-time: strength-reduce addresses)
#define SM ((size_t)M_ROWS * D_DIM)      // elements per state buffer
#define WM ((size_t)D_DIM * D_DIM)       // elements per W

__device__ __forceinline__ u16 f2b(float f) {
    union { float f; unsigned u; } c; c.f = f;
    unsigned u = c.u;
    u = (u + 0x7FFFu + ((u >> 16) & 1u)) >> 16;   // RNE
    return (u16)u;
}
__device__ __forceinline__ float b2f(u16 b) {
    union { unsigned u; float f; } c; c.u = ((unsigned)b) << 16;
    return c.f;
}
__device__ __forceinline__ unsigned pk2(float a, float b) {
    return (unsigned)f2b(a) | ((unsigned)f2b(b) << 16);
}

// async 16B global -> LDS (wave-uniform LDS base + lane*16)
__device__ __forceinline__ void ld16(const u16* g, u16* l) {
    __builtin_amdgcn_global_load_lds(
        (const __attribute__((address_space(1))) void*)g,
        (__attribute__((address_space(3))) void*)l, 16, 0, 0);
}

// ---------------------------------------------------------------------------
// Shared GEMM core: C(128x128 f32 acc) = A(M x 1024 bf16, row-major)
//                                      @ B^T(N x 1024 bf16, row-major)
// 256 threads = 4 waves in 2x2; each wave 64x64 = 4x4 frags of 16x16x32 MFMA.
// global_load_lds width=16 staging into stride-32 LDS with XOR chunk swizzle
// (conflict-free, verified R3: SQ_LDS_BANK_CONFLICT == 0).
// smem: caller-provided 8192 u16 (a tile = [0,4096), b tile = [4096,8192)).
// Register budget matters: target 4 blocks/CU (<=128 VGPR+AGPR per wave).
// ---------------------------------------------------------------------------
__device__ __forceinline__ void gemm_core(const u16* __restrict__ A,
                                          const u16* __restrict__ B,
                                          int m0, int n0,
                                          floatx4 (&acc)[4][4],
                                          u16* smem) {
    u16* a_lds = smem;
    u16* b_lds = smem + 4096;
    const int tid  = threadIdx.x;
    const int lane = tid & 63;
    const int wave = tid >> 6;
    const int wm = wave >> 1, wn = wave & 1;
    const int q = lane >> 4, lr = lane & 15;
    const int qs = q ^ ((lr >> 1) & 3);          // read-side swizzle

    const int r0 = wave * 16 + (lane >> 2);
    const int cc = ((lane & 3) ^ ((lane >> 3) & 3)) * 8;
    const u16* ga = A + ((size_t)(m0 + r0) << 10) + cc;   // row stride 1024
    const u16* gb = B + ((size_t)(n0 + r0) << 10) + cc;
    u16* la = &a_lds[wave * 512];
    u16* lb = &b_lds[wave * 512];

    #pragma unroll
    for (int i = 0; i < 4; i++)
        #pragma unroll
        for (int j = 0; j < 4; j++)
            acc[i][j] = floatx4{0.f, 0.f, 0.f, 0.f};

    for (int kt = 0; kt < KDIM; kt += 32) {
        __syncthreads();                 // previous iter's LDS reads done
        ld16(ga + kt, la);
        ld16(ga + (64 << 10) + kt, la + 2048);   // +64 rows, derived not live
        ld16(gb + kt, lb);
        ld16(gb + (64 << 10) + kt, lb + 2048);
        __syncthreads();                 // drains vmcnt before reads
        bf16x8 af[4], bfv[4];
        #pragma unroll
        for (int mi = 0; mi < 4; mi++)
            af[mi] = *(const bf16x8*)&a_lds[(wm * 64 + mi * 16 + lr) * 32 + qs * 8];
        #pragma unroll
        for (int ni = 0; ni < 4; ni++)
            bfv[ni] = *(const bf16x8*)&b_lds[(wn * 64 + ni * 16 + lr) * 32 + qs * 8];
        #pragma unroll
        for (int mi = 0; mi < 4; mi++)
            #pragma unroll
            for (int ni = 0; ni < 4; ni++)
                acc[mi][ni] = __builtin_amdgcn_mfma_f32_16x16x32_bf16(
                    af[mi], bfv[ni], acc[mi][ni], 0, 0, 0);
    }
}

// Epilogue staging map (32 rows x 128 cols bf16 per pass, 8KB in smem[0..4095]):
//   slot row  = wm*16 + q*4 + r  (global row = m0 + (row>>4)*64 + mi*16 + (row&15))
//   col chunk rotation: slot_chunk = (chunk + 4*((row>>2)&3)) & 15  -> both LDS
//   phases uniform 2-way bank touches (free).

// eps_l = lower - b - mu_l @ W^T. If pc_accum==null: write eps as bf16 (16B
// coalesced). Else: skip the write, accumulate sum(eps^2) into *pc_accum.
__global__ __launch_bounds__(256, 4) void eps_gemm_k(
        const u16* __restrict__ sbf, const u16* __restrict__ Wbf,
        const u16* __restrict__ xbf, const float* __restrict__ b_stack,
        u16* __restrict__ epsb, float* __restrict__ pc_accum) {
    __shared__ __align__(16) u16 smem[8192];
    const int z = blockIdx.z;
    const int m0 = blockIdx.y * 128, n0 = blockIdx.x * 128;
    floatx4 acc[4][4];
    gemm_core(sbf + (size_t)z * SM, Wbf + (size_t)z * WM, m0, n0, acc, smem);
    const u16* lower = (z == 0) ? xbf : (sbf + (size_t)(z - 1) * SM);
    const float* bias = b_stack + z * D_DIM;
    u16* eo = epsb + (size_t)z * SM;
    const int tid = threadIdx.x, lane = tid & 63, wave = tid >> 6;
    const int wm = wave >> 1, wn = wave & 1, q = lane >> 4, lr = lane & 15;
    float sq = 0.f;
    #pragma unroll
    for (int mi = 0; mi < 4; mi++) {
        __syncthreads();
        #pragma unroll
        for (int ni = 0; ni < 4; ni++) {
            const int col = wn * 64 + ni * 16 + lr;
            const float bc = bias[n0 + col];
            #pragma unroll
            for (int r = 0; r < 4; r++) {
                const int row = wm * 16 + q * 4 + r;
                const int scn = ((col >> 3) + ((row >> 2) & 3) * 4) & 15;
                smem[row * 128 + scn * 8 + (col & 7)] = f2b(acc[mi][ni][r] + bc);
            }
        }
        __syncthreads();
        #pragma unroll
        for (int h = 0; h < 2; h++) {
            const int c = tid + h * 256;
            const int lrow = c >> 4, ch = c & 15;
            const int scn = (ch + ((lrow >> 2) & 3) * 4) & 15;
            const int grow = m0 + (lrow >> 4) * 64 + mi * 16 + (lrow & 15);
            const size_t gidx = (size_t)grow * D_DIM + n0 + ch * 8;
            bf16x8 st = *(const bf16x8*)&smem[lrow * 128 + scn * 8];
            bf16x8 lo = *(const bf16x8*)(lower + gidx);
            float e[8];
            #pragma unroll
            for (int i = 0; i < 8; i++) e[i] = (float)lo[i] - (float)st[i];
            if (pc_accum) {
                #pragma unroll
                for (int i = 0; i < 8; i++) sq += e[i] * e[i];
            } else {
                uint4 ov;
                ov.x = pk2(e[0], e[1]); ov.y = pk2(e[2], e[3]);
                ov.z = pk2(e[4], e[5]); ov.w = pk2(e[6], e[7]);
                *(uint4*)(eo + gidx) = ov;
            }
        }
    }
    if (pc_accum) {
        #pragma unroll
        for (int off = 1; off < 64; off <<= 1) sq += __shfl_xor(sq, off, 64);
        __shared__ float ls[4];
        if (lane == 0) ls[wave] = sq;
        __syncthreads();
        if (tid == 0) atomicAdd(pc_accum, ls[0] + ls[1] + ls[2] + ls[3]);
    }
}

// s_l += LR*(eps_l @ W) - LR*eps_{l+1};  states live as bf16 only
__global__ __launch_bounds__(256, 4) void upd_gemm_k(
        const u16* __restrict__ epsb, const u16* __restrict__ WTbf,
        u16* __restrict__ sbf) {
    __shared__ __align__(16) u16 smem[8192];
    const int z = blockIdx.z;
    const int m0 = blockIdx.y * 128, n0 = blockIdx.x * 128;
    floatx4 acc[4][4];
    gemm_core(epsb + (size_t)z * SM, WTbf + (size_t)z * WM, m0, n0, acc, smem);
    u16* Sb = sbf + (size_t)z * SM;
    const bool hn = (z < 3);
    const u16* en = epsb + (size_t)(hn ? (z + 1) : z) * SM;
    const int tid = threadIdx.x, lane = tid & 63, wave = tid >> 6;
    const int wm = wave >> 1, wn = wave & 1, q = lane >> 4, lr = lane & 15;
    #pragma unroll
    for (int mi = 0; mi < 4; mi++) {
        __syncthreads();
        #pragma unroll
        for (int ni = 0; ni < 4; ni++) {
            const int col = wn * 64 + ni * 16 + lr;
            #pragma unroll
            for (int r = 0; r < 4; r++) {
                const int row = wm * 16 + q * 4 + r;
                const int scn = ((col >> 3) + ((row >> 2) & 3) * 4) & 15;
                smem[row * 128 + scn * 8 + (col & 7)] = f2b(LRS * acc[mi][ni][r]);
            }
        }
        __syncthreads();
        #pragma unroll
        for (int h = 0; h < 2; h++) {
            const int c = tid + h * 256;
            const int lrow = c >> 4, ch = c & 15;
            const int scn = (ch + ((lrow >> 2) & 3) * 4) & 15;
            const int grow = m0 + (lrow >> 4) * 64 + mi * 16 + (lrow & 15);
            const size_t gidx = (size_t)grow * D_DIM + n0 + ch * 8;
            bf16x8 st = *(const bf16x8*)&smem[lrow * 128 + scn * 8];
            bf16x8 S8 = *(const bf16x8*)(Sb + gidx);
            float v[8];
            #pragma unroll
            for (int i = 0; i < 8; i++) v[i] = (float)S8[i] + (float)st[i];
            if (hn) {
                bf16x8 e8 = *(const bf16x8*)(en + gidx);
                #pragma unroll
                for (int i = 0; i < 8; i++) v[i] -= LRS * (float)e8[i];
            }
            uint4 ov;
            ov.x = pk2(v[0], v[1]); ov.y = pk2(v[2], v[3]);
            ov.z = pk2(v[4], v[5]); ov.w = pk2(v[6], v[7]);
            *(uint4*)(Sb + gidx) = ov;
        }
    }
}

// logits tile + fused online-softmax partials + target-logit capture
// grid: x = m-tile (32, fastest) so co-resident blocks share one B n-strip
__global__ __launch_bounds__(256, 4) void logits_k(
        const u16* __restrict__ s4bf, const u16* __restrict__ oWb,
        const float* __restrict__ out_b, const int* __restrict__ targets,
        float* __restrict__ part_m, float* __restrict__ part_s,
        float* __restrict__ tlog) {
    __shared__ __align__(16) u16 smem[8192];
    const int m0 = blockIdx.x * 128, n0 = blockIdx.y * 128;
    floatx4 acc[4][4];
    gemm_core(s4bf, oWb, m0, n0, acc, smem);
    __shared__ float redm[128][2];
    __shared__ float reds[128][2];
    const int tid = threadIdx.x, lane = tid & 63, wave = tid >> 6;
    const int wm = wave >> 1, wn = wave & 1, q = lane >> 4, lr = lane & 15;
    float ob[4];
    #pragma unroll
    for (int ni = 0; ni < 4; ni++) ob[ni] = out_b[n0 + wn * 64 + ni * 16 + lr];
    #pragma unroll
    for (int mi = 0; mi < 4; mi++) {
        #pragma unroll
        for (int r = 0; r < 4; r++) {
            const int grow = m0 + wm * 64 + mi * 16 + q * 4 + r;
            float l[4];
            #pragma unroll
            for (int ni = 0; ni < 4; ni++) l[ni] = acc[mi][ni][r] + ob[ni];
            if ((grow & 511) != 511) {           // valid row (s < 511)
                const int t = targets[grow + 1];
                #pragma unroll
                for (int ni = 0; ni < 4; ni++) {
                    const int gcol = n0 + wn * 64 + ni * 16 + lr;
                    if (t == gcol) tlog[grow] = l[ni];
                }
            }
            float mx = fmaxf(fmaxf(l[0], l[1]), fmaxf(l[2], l[3]));
            #pragma unroll
            for (int off = 1; off < 16; off <<= 1)
                mx = fmaxf(mx, __shfl_xor(mx, off, 64));
            float sm = __expf(l[0] - mx) + __expf(l[1] - mx) +
                       __expf(l[2] - mx) + __expf(l[3] - mx);
            #pragma unroll
            for (int off = 1; off < 16; off <<= 1)
                sm += __shfl_xor(sm, off, 64);
            if (lr == 0) {
                const int rrow = wm * 64 + mi * 16 + q * 4 + r;
                redm[rrow][wn] = mx;
                reds[rrow][wn] = sm;
            }
        }
    }
    __syncthreads();
    if (tid < 128) {
        float ma = redm[tid][0], mb = redm[tid][1];
        float M = fmaxf(ma, mb);
        float S = reds[tid][0] * __expf(ma - M) + reds[tid][1] * __expf(mb - M);
        part_m[(size_t)blockIdx.y * M_ROWS + m0 + tid] = M;
        part_s[(size_t)blockIdx.y * M_ROWS + m0 + tid] = S;
    }
}

__global__ void gather_k(const int* __restrict__ ids,
                         const float* __restrict__ emb,
                         u16* __restrict__ xbf) {
    const int row = blockIdx.x;
    const int c = threadIdx.x * 4;
    float4 v = *(const float4*)(emb + (size_t)ids[row] * D_DIM + c);
    uint2 o; o.x = pk2(v.x, v.y); o.y = pk2(v.z, v.w);
    *(uint2*)(xbf + (size_t)row * D_DIM + c) = o;
}

__global__ void conv_w_k(const float* __restrict__ W,
                         u16* __restrict__ Wbf, u16* __restrict__ WTbf) {
    __shared__ float t[32][33];
    const int z = blockIdx.z;
    const int i = blockIdx.y * 32 + threadIdx.y;
    const int j = blockIdx.x * 32 + threadIdx.x;
    const float v = W[(size_t)z * WM + (size_t)i * D_DIM + j];
    Wbf[(size_t)z * WM + (size_t)i * D_DIM + j] = f2b(v);
    t[threadIdx.y][threadIdx.x] = v;
    __syncthreads();
    const int jo = blockIdx.x * 32 + threadIdx.y;
    const int io = blockIdx.y * 32 + threadIdx.x;
    WTbf[(size_t)z * WM + (size_t)jo * D_DIM + io] = f2b(t[threadIdx.x][threadIdx.y]);
}

__global__ void conv_outw_k(const float* __restrict__ oW, u16* __restrict__ oWb) {
    const size_t i = ((size_t)blockIdx.x * 256 + threadIdx.x) * 4;
    float4 v = *(const float4*)(oW + i);
    uint2 o; o.x = pk2(v.x, v.y); o.y = pk2(v.z, v.w);
    *(uint2*)(oWb + i) = o;
}

__global__ void init_states_k(const float* __restrict__ si,
                              u16* __restrict__ sbf) {
    const size_t i = ((size_t)blockIdx.x * 256 + threadIdx.x) * 4;
    float4 v = *(const float4*)(si + i);
    uint2 o; o.x = pk2(v.x, v.y); o.y = pk2(v.z, v.w);
    *(uint2*)(sbf + i) = o;
}

__global__ void ce_reduce_k(const float* __restrict__ part_m,
                            const float* __restrict__ part_s,
                            const float* __restrict__ tlog,
                            float* __restrict__ ce_sum) {
    const int row = blockIdx.x;
    if ((row & 511) == 511) return;
    const int tid = threadIdx.x;
    const int NT = V_DIM / 128;  // 250
    float m = -3.0e38f;
    for (int nt = tid; nt < NT; nt += 256)
        m = fmaxf(m, part_m[(size_t)nt * M_ROWS + row]);
    #pragma unroll
    for (int off = 1; off < 64; off <<= 1) m = fmaxf(m, __shfl_xor(m, off, 64));
    __shared__ float sm[4], ss[4];
    if ((tid & 63) == 0) sm[tid >> 6] = m;
    __syncthreads();
    m = fmaxf(fmaxf(sm[0], sm[1]), fmaxf(sm[2], sm[3]));
    float s = 0.f;
    for (int nt = tid; nt < NT; nt += 256)
        s += part_s[(size_t)nt * M_ROWS + row] *
             __expf(part_m[(size_t)nt * M_ROWS + row] - m);
    #pragma unroll
    for (int off = 1; off < 64; off <<= 1) s += __shfl_xor(s, off, 64);
    if ((tid & 63) == 0) ss[tid >> 6] = s;
    __syncthreads();
    if (tid == 0) {
        float loss = m + __logf(ss[0] + ss[1] + ss[2] + ss[3]) - tlog[row];
        atomicAdd(ce_sum, loss);
    }
}

__global__ void finalize_k(const float* __restrict__ scal, float* __restrict__ out) {
    out[0] = scal[0] / 4088.0f;
    out[1] = scal[1] / (float)(4 * SM);
}

extern "C" void kernel_launch(void* const* d_in, const int* in_sizes, int n_in,
                              void* d_out, int out_size, void* d_ws, size_t ws_size,
                              hipStream_t stream) {
    (void)in_sizes; (void)n_in; (void)out_size; (void)ws_size;
    const int*   ids = (const int*)d_in[0];
    const int*   tgt = (const int*)d_in[1];
    const float* emb = (const float*)d_in[2];
    const float* W   = (const float*)d_in[3];
    const float* bs  = (const float*)d_in[4];
    const float* oW  = (const float*)d_in[5];
    const float* ob  = (const float*)d_in[6];
    const float* si  = (const float*)d_in[7];

    char* ws = (char*)d_ws;
    u16*   sbf    = (u16*)  (ws + 0);             // 33,554,432 B
    u16*   epsb   = (u16*)  (ws + 33554432);      // 33,554,432 B
    u16*   xbf    = (u16*)  (ws + 67108864);      //  8,388,608 B
    u16*   Wbf    = (u16*)  (ws + 75497472);      //  8,388,608 B
    u16*   WTbf   = (u16*)  (ws + 83886080);      //  8,388,608 B
    u16*   oWb    = (u16*)  (ws + 92274688);      // 65,536,000 B
    float* part_m = (float*)(ws + 157810688);     //  4,096,000 B
    float* part_s = (float*)(ws + 161906688);     //  4,096,000 B
    float* tlog   = (float*)(ws + 166002688);     //     16,384 B
    float* scal   = (float*)(ws + 166019072);     //        256 B

    hipMemsetAsync(scal, 0, 256, stream);
    gather_k<<<M_ROWS, 256, 0, stream>>>(ids, emb, xbf);
    conv_w_k<<<dim3(32, 32, 4), dim3(32, 32), 0, stream>>>(W, Wbf, WTbf);
    conv_outw_k<<<(V_DIM * D_DIM) / 1024, 256, 0, stream>>>(oW, oWb);
    init_states_k<<<(4 * (int)SM) / 1024, 256, 0, stream>>>(si, sbf);

    for (int step = 0; step < STEPS; ++step) {
        eps_gemm_k<<<dim3(8, 32, 4), 256, 0, stream>>>(sbf, Wbf, xbf, bs, epsb,
                                                       nullptr);
        upd_gemm_k<<<dim3(8, 32, 4), 256, 0, stream>>>(epsb, WTbf, sbf);
    }
    // final eps pass: no eps write, accumulate sum(eps^2) directly
    eps_gemm_k<<<dim3(8, 32, 4), 256, 0, stream>>>(sbf, Wbf, xbf, bs, epsb,
                                                   scal + 1);
    logits_k<<<dim3(32, V_DIM / 128), 256, 0, stream>>>(sbf + 3 * SM, oWb, ob, tgt,
                                                        part_m, part_s, tlog);
    ce_reduce_k<<<M_ROWS, 256, 0, stream>>>(part_m, part_s, tlog, scal);
    finalize_k<<<1, 1, 0, stream>>>(scal, (float*)d_out);
}

// Round 6
// 1620.129 us; speedup vs baseline: 1.4159x; 1.0131x over previous
//
#include <hip/hip_runtime.h>

typedef unsigned short u16;
typedef __attribute__((ext_vector_type(8))) __bf16 bf16x8;
typedef __attribute__((ext_vector_type(4))) float floatx4;

#define NUM_LAYERS 4
#define STEPS 8
#define LRS 0.1f
#define M_ROWS 4096            // B*S
#define D_DIM 1024
#define V_DIM 32000
#define KDIM 1024              // GEMM K (compile-time: strength-reduce addresses)
#define SM ((size_t)M_ROWS * D_DIM)      // elements per state buffer
#define WM ((size_t)D_DIM * D_DIM)       // elements per W

__device__ __forceinline__ u16 f2b(float f) {
    union { float f; unsigned u; } c; c.f = f;
    unsigned u = c.u;
    u = (u + 0x7FFFu + ((u >> 16) & 1u)) >> 16;   // RNE
    return (u16)u;
}
__device__ __forceinline__ float b2f(u16 b) {
    union { unsigned u; float f; } c; c.u = ((unsigned)b) << 16;
    return c.f;
}
__device__ __forceinline__ unsigned pk2(float a, float b) {
    return (unsigned)f2b(a) | ((unsigned)f2b(b) << 16);
}

// async 16B global -> LDS (wave-uniform LDS base + lane*16)
__device__ __forceinline__ void ld16(const u16* g, u16* l) {
    __builtin_amdgcn_global_load_lds(
        (const __attribute__((address_space(1))) void*)g,
        (__attribute__((address_space(3))) void*)l, 16, 0, 0);
}

// ---------------------------------------------------------------------------
// Shared GEMM core: C(128x128 f32 acc) = A(M x 1024 bf16, row-major)
//                                      @ B^T(N x 1024 bf16, row-major)
// 256 threads = 4 waves in 2x2; each wave 64x64 = 4x4 frags of 16x16x32 MFMA.
// BK=64 K-tile stored as TWO 32-col sub-tiles (each the verified conflict-free
// XOR-swizzled stride-32 layout) -> halves the barrier count vs BK=32 while
// reusing the same 4 staging base addresses (+64B imm offset for the 2nd half;
// no extra VGPRs, unlike m132's BK=128 which cost occupancy).
// smem: caller-provided 16384 u16 (A halves [0,8192), B halves [8192,16384)).
// Register budget: keep 4 blocks/CU (<=64 arch VGPRs; LDS 4x~34KB <160KB).
// ---------------------------------------------------------------------------
__device__ __forceinline__ void gemm_core(const u16* __restrict__ A,
                                          const u16* __restrict__ B,
                                          int m0, int n0,
                                          floatx4 (&acc)[4][4],
                                          u16* smem) {
    u16* a_lds = smem;           // [2][4096] halves
    u16* b_lds = smem + 8192;
    const int tid  = threadIdx.x;
    const int lane = tid & 63;
    const int wave = tid >> 6;
    const int wm = wave >> 1, wn = wave & 1;
    const int q = lane >> 4, lr = lane & 15;
    const int qs = q ^ ((lr >> 1) & 3);          // read-side swizzle

    const int r0 = wave * 16 + (lane >> 2);
    const int cc = ((lane & 3) ^ ((lane >> 3) & 3)) * 8;
    const u16* ga = A + ((size_t)(m0 + r0) << 10) + cc;   // row stride 1024
    const u16* gb = B + ((size_t)(n0 + r0) << 10) + cc;
    u16* la = &a_lds[wave * 512];
    u16* lb = &b_lds[wave * 512];

    #pragma unroll
    for (int i = 0; i < 4; i++)
        #pragma unroll
        for (int j = 0; j < 4; j++)
            acc[i][j] = floatx4{0.f, 0.f, 0.f, 0.f};

    for (int kt = 0; kt < KDIM; kt += 64) {
        __syncthreads();                 // previous iter's LDS reads done
        ld16(ga + kt,                  la);
        ld16(ga + kt + 32,             la + 4096);
        ld16(ga + (64 << 10) + kt,     la + 2048);
        ld16(ga + (64 << 10) + kt + 32, la + 2048 + 4096);
        ld16(gb + kt,                  lb);
        ld16(gb + kt + 32,             lb + 4096);
        ld16(gb + (64 << 10) + kt,     lb + 2048);
        ld16(gb + (64 << 10) + kt + 32, lb + 2048 + 4096);
        __syncthreads();                 // drains vmcnt before reads
        #pragma unroll
        for (int h = 0; h < 2; h++) {
            bf16x8 af[4], bfv[4];
            #pragma unroll
            for (int mi = 0; mi < 4; mi++)
                af[mi] = *(const bf16x8*)
                    &a_lds[h * 4096 + (wm * 64 + mi * 16 + lr) * 32 + qs * 8];
            #pragma unroll
            for (int ni = 0; ni < 4; ni++)
                bfv[ni] = *(const bf16x8*)
                    &b_lds[h * 4096 + (wn * 64 + ni * 16 + lr) * 32 + qs * 8];
            #pragma unroll
            for (int mi = 0; mi < 4; mi++)
                #pragma unroll
                for (int ni = 0; ni < 4; ni++)
                    acc[mi][ni] = __builtin_amdgcn_mfma_f32_16x16x32_bf16(
                        af[mi], bfv[ni], acc[mi][ni], 0, 0, 0);
        }
    }
}

// Epilogue staging map (32 rows x 128 cols bf16 per pass, 8KB in smem[0..4095]):
//   slot row  = wm*16 + q*4 + r  (global row = m0 + (row>>4)*64 + mi*16 + (row&15))
//   col chunk rotation: slot_chunk = (chunk + 4*((row>>2)&3)) & 15  -> both LDS
//   phases uniform 2-way bank touches (free).

// eps_l = lower - b - mu_l @ W^T. If pc_accum==null: write eps as bf16 (16B
// coalesced). Else: skip the write, accumulate sum(eps^2) into *pc_accum.
__global__ __launch_bounds__(256, 4) void eps_gemm_k(
        const u16* __restrict__ sbf, const u16* __restrict__ Wbf,
        const u16* __restrict__ xbf, const float* __restrict__ b_stack,
        u16* __restrict__ epsb, float* __restrict__ pc_accum) {
    __shared__ __align__(16) u16 smem[16384];
    const int z = blockIdx.z;
    const int m0 = blockIdx.y * 128, n0 = blockIdx.x * 128;
    floatx4 acc[4][4];
    gemm_core(sbf + (size_t)z * SM, Wbf + (size_t)z * WM, m0, n0, acc, smem);
    const u16* lower = (z == 0) ? xbf : (sbf + (size_t)(z - 1) * SM);
    const float* bias = b_stack + z * D_DIM;
    u16* eo = epsb + (size_t)z * SM;
    const int tid = threadIdx.x, lane = tid & 63, wave = tid >> 6;
    const int wm = wave >> 1, wn = wave & 1, q = lane >> 4, lr = lane & 15;
    float sq = 0.f;
    #pragma unroll
    for (int mi = 0; mi < 4; mi++) {
        __syncthreads();
        #pragma unroll
        for (int ni = 0; ni < 4; ni++) {
            const int col = wn * 64 + ni * 16 + lr;
            const float bc = bias[n0 + col];
            #pragma unroll
            for (int r = 0; r < 4; r++) {
                const int row = wm * 16 + q * 4 + r;
                const int scn = ((col >> 3) + ((row >> 2) & 3) * 4) & 15;
                smem[row * 128 + scn * 8 + (col & 7)] = f2b(acc[mi][ni][r] + bc);
            }
        }
        __syncthreads();
        #pragma unroll
        for (int h = 0; h < 2; h++) {
            const int c = tid + h * 256;
            const int lrow = c >> 4, ch = c & 15;
            const int scn = (ch + ((lrow >> 2) & 3) * 4) & 15;
            const int grow = m0 + (lrow >> 4) * 64 + mi * 16 + (lrow & 15);
            const size_t gidx = (size_t)grow * D_DIM + n0 + ch * 8;
            bf16x8 st = *(const bf16x8*)&smem[lrow * 128 + scn * 8];
            bf16x8 lo = *(const bf16x8*)(lower + gidx);
            float e[8];
            #pragma unroll
            for (int i = 0; i < 8; i++) e[i] = (float)lo[i] - (float)st[i];
            if (pc_accum) {
                #pragma unroll
                for (int i = 0; i < 8; i++) sq += e[i] * e[i];
            } else {
                uint4 ov;
                ov.x = pk2(e[0], e[1]); ov.y = pk2(e[2], e[3]);
                ov.z = pk2(e[4], e[5]); ov.w = pk2(e[6], e[7]);
                *(uint4*)(eo + gidx) = ov;
            }
        }
    }
    if (pc_accum) {
        #pragma unroll
        for (int off = 1; off < 64; off <<= 1) sq += __shfl_xor(sq, off, 64);
        __shared__ float ls[4];
        if (lane == 0) ls[wave] = sq;
        __syncthreads();
        if (tid == 0) atomicAdd(pc_accum, ls[0] + ls[1] + ls[2] + ls[3]);
    }
}

// s_l += LR*(eps_l @ W) - LR*eps_{l+1};  states live as bf16 only
__global__ __launch_bounds__(256, 4) void upd_gemm_k(
        const u16* __restrict__ epsb, const u16* __restrict__ WTbf,
        u16* __restrict__ sbf) {
    __shared__ __align__(16) u16 smem[16384];
    const int z = blockIdx.z;
    const int m0 = blockIdx.y * 128, n0 = blockIdx.x * 128;
    floatx4 acc[4][4];
    gemm_core(epsb + (size_t)z * SM, WTbf + (size_t)z * WM, m0, n0, acc, smem);
    u16* Sb = sbf + (size_t)z * SM;
    const bool hn = (z < 3);
    const u16* en = epsb + (size_t)(hn ? (z + 1) : z) * SM;
    const int tid = threadIdx.x, lane = tid & 63, wave = tid >> 6;
    const int wm = wave >> 1, wn = wave & 1, q = lane >> 4, lr = lane & 15;
    #pragma unroll
    for (int mi = 0; mi < 4; mi++) {
        __syncthreads();
        #pragma unroll
        for (int ni = 0; ni < 4; ni++) {
            const int col = wn * 64 + ni * 16 + lr;
            #pragma unroll
            for (int r = 0; r < 4; r++) {
                const int row = wm * 16 + q * 4 + r;
                const int scn = ((col >> 3) + ((row >> 2) & 3) * 4) & 15;
                smem[row * 128 + scn * 8 + (col & 7)] = f2b(LRS * acc[mi][ni][r]);
            }
        }
        __syncthreads();
        #pragma unroll
        for (int h = 0; h < 2; h++) {
            const int c = tid + h * 256;
            const int lrow = c >> 4, ch = c & 15;
            const int scn = (ch + ((lrow >> 2) & 3) * 4) & 15;
            const int grow = m0 + (lrow >> 4) * 64 + mi * 16 + (lrow & 15);
            const size_t gidx = (size_t)grow * D_DIM + n0 + ch * 8;
            bf16x8 st = *(const bf16x8*)&smem[lrow * 128 + scn * 8];
            bf16x8 S8 = *(const bf16x8*)(Sb + gidx);
            float v[8];
            #pragma unroll
            for (int i = 0; i < 8; i++) v[i] = (float)S8[i] + (float)st[i];
            if (hn) {
                bf16x8 e8 = *(const bf16x8*)(en + gidx);
                #pragma unroll
                for (int i = 0; i < 8; i++) v[i] -= LRS * (float)e8[i];
            }
            uint4 ov;
            ov.x = pk2(v[0], v[1]); ov.y = pk2(v[2], v[3]);
            ov.z = pk2(v[4], v[5]); ov.w = pk2(v[6], v[7]);
            *(uint4*)(Sb + gidx) = ov;
        }
    }
}

// logits tile + fused online-softmax partials + target-logit capture
// grid: x = m-tile (32, fastest) so co-resident blocks share one B n-strip
__global__ __launch_bounds__(256, 4) void logits_k(
        const u16* __restrict__ s4bf, const u16* __restrict__ oWb,
        const float* __restrict__ out_b, const int* __restrict__ targets,
        float* __restrict__ part_m, float* __restrict__ part_s,
        float* __restrict__ tlog) {
    __shared__ __align__(16) u16 smem[16384];
    const int m0 = blockIdx.x * 128, n0 = blockIdx.y * 128;
    floatx4 acc[4][4];
    gemm_core(s4bf, oWb, m0, n0, acc, smem);
    __shared__ float redm[128][2];
    __shared__ float reds[128][2];
    const int tid = threadIdx.x, lane = tid & 63, wave = tid >> 6;
    const int wm = wave >> 1, wn = wave & 1, q = lane >> 4, lr = lane & 15;
    float ob[4];
    #pragma unroll
    for (int ni = 0; ni < 4; ni++) ob[ni] = out_b[n0 + wn * 64 + ni * 16 + lr];
    #pragma unroll
    for (int mi = 0; mi < 4; mi++) {
        #pragma unroll
        for (int r = 0; r < 4; r++) {
            const int grow = m0 + wm * 64 + mi * 16 + q * 4 + r;
            float l[4];
            #pragma unroll
            for (int ni = 0; ni < 4; ni++) l[ni] = acc[mi][ni][r] + ob[ni];
            if ((grow & 511) != 511) {           // valid row (s < 511)
                const int t = targets[grow + 1];
                #pragma unroll
                for (int ni = 0; ni < 4; ni++) {
                    const int gcol = n0 + wn * 64 + ni * 16 + lr;
                    if (t == gcol) tlog[grow] = l[ni];
                }
            }
            float mx = fmaxf(fmaxf(l[0], l[1]), fmaxf(l[2], l[3]));
            #pragma unroll
            for (int off = 1; off < 16; off <<= 1)
                mx = fmaxf(mx, __shfl_xor(mx, off, 64));
            float sm = __expf(l[0] - mx) + __expf(l[1] - mx) +
                       __expf(l[2] - mx) + __expf(l[3] - mx);
            #pragma unroll
            for (int off = 1; off < 16; off <<= 1)
                sm += __shfl_xor(sm, off, 64);
            if (lr == 0) {
                const int rrow = wm * 64 + mi * 16 + q * 4 + r;
                redm[rrow][wn] = mx;
                reds[rrow][wn] = sm;
            }
        }
    }
    __syncthreads();
    if (tid < 128) {
        float ma = redm[tid][0], mb = redm[tid][1];
        float M = fmaxf(ma, mb);
        float S = reds[tid][0] * __expf(ma - M) + reds[tid][1] * __expf(mb - M);
        part_m[(size_t)blockIdx.y * M_ROWS + m0 + tid] = M;
        part_s[(size_t)blockIdx.y * M_ROWS + m0 + tid] = S;
    }
}

__global__ void gather_k(const int* __restrict__ ids,
                         const float* __restrict__ emb,
                         u16* __restrict__ xbf) {
    const int row = blockIdx.x;
    const int c = threadIdx.x * 4;
    float4 v = *(const float4*)(emb + (size_t)ids[row] * D_DIM + c);
    uint2 o; o.x = pk2(v.x, v.y); o.y = pk2(v.z, v.w);
    *(uint2*)(xbf + (size_t)row * D_DIM + c) = o;
}

__global__ void conv_w_k(const float* __restrict__ W,
                         u16* __restrict__ Wbf, u16* __restrict__ WTbf) {
    __shared__ float t[32][33];
    const int z = blockIdx.z;
    const int i = blockIdx.y * 32 + threadIdx.y;
    const int j = blockIdx.x * 32 + threadIdx.x;
    const float v = W[(size_t)z * WM + (size_t)i * D_DIM + j];
    Wbf[(size_t)z * WM + (size_t)i * D_DIM + j] = f2b(v);
    t[threadIdx.y][threadIdx.x] = v;
    __syncthreads();
    const int jo = blockIdx.x * 32 + threadIdx.y;
    const int io = blockIdx.y * 32 + threadIdx.x;
    WTbf[(size_t)z * WM + (size_t)jo * D_DIM + io] = f2b(t[threadIdx.x][threadIdx.y]);
}

__global__ void conv_outw_k(const float* __restrict__ oW, u16* __restrict__ oWb) {
    const size_t i = ((size_t)blockIdx.x * 256 + threadIdx.x) * 4;
    float4 v = *(const float4*)(oW + i);
    uint2 o; o.x = pk2(v.x, v.y); o.y = pk2(v.z, v.w);
    *(uint2*)(oWb + i) = o;
}

__global__ void init_states_k(const float* __restrict__ si,
                              u16* __restrict__ sbf) {
    const size_t i = ((size_t)blockIdx.x * 256 + threadIdx.x) * 4;
    float4 v = *(const float4*)(si + i);
    uint2 o; o.x = pk2(v.x, v.y); o.y = pk2(v.z, v.w);
    *(uint2*)(sbf + i) = o;
}

__global__ void ce_reduce_k(const float* __restrict__ part_m,
                            const float* __restrict__ part_s,
                            const float* __restrict__ tlog,
                            float* __restrict__ ce_sum) {
    const int row = blockIdx.x;
    if ((row & 511) == 511) return;
    const int tid = threadIdx.x;
    const int NT = V_DIM / 128;  // 250
    float m = -3.0e38f;
    for (int nt = tid; nt < NT; nt += 256)
        m = fmaxf(m, part_m[(size_t)nt * M_ROWS + row]);
    #pragma unroll
    for (int off = 1; off < 64; off <<= 1) m = fmaxf(m, __shfl_xor(m, off, 64));
    __shared__ float sm[4], ss[4];
    if ((tid & 63) == 0) sm[tid >> 6] = m;
    __syncthreads();
    m = fmaxf(fmaxf(sm[0], sm[1]), fmaxf(sm[2], sm[3]));
    float s = 0.f;
    for (int nt = tid; nt < NT; nt += 256)
        s += part_s[(size_t)nt * M_ROWS + row] *
             __expf(part_m[(size_t)nt * M_ROWS + row] - m);
    #pragma unroll
    for (int off = 1; off < 64; off <<= 1) s += __shfl_xor(s, off, 64);
    if ((tid & 63) == 0) ss[tid >> 6] = s;
    __syncthreads();
    if (tid == 0) {
        float loss = m + __logf(ss[0] + ss[1] + ss[2] + ss[3]) - tlog[row];
        atomicAdd(ce_sum, loss);
    }
}

__global__ void finalize_k(const float* __restrict__ scal, float* __restrict__ out) {
    out[0] = scal[0] / 4088.0f;
    out[1] = scal[1] / (float)(4 * SM);
}

extern "C" void kernel_launch(void* const* d_in, const int* in_sizes, int n_in,
                              void* d_out, int out_size, void* d_ws, size_t ws_size,
                              hipStream_t stream) {
    (void)in_sizes; (void)n_in; (void)out_size; (void)ws_size;
    const int*   ids = (const int*)d_in[0];
    const int*   tgt = (const int*)d_in[1];
    const float* emb = (const float*)d_in[2];
    const float* W   = (const float*)d_in[3];
    const float* bs  = (const float*)d_in[4];
    const float* oW  = (const float*)d_in[5];
    const float* ob  = (const float*)d_in[6];
    const float* si  = (const float*)d_in[7];

    char* ws = (char*)d_ws;
    u16*   sbf    = (u16*)  (ws + 0);             // 33,554,432 B
    u16*   epsb   = (u16*)  (ws + 33554432);      // 33,554,432 B
    u16*   xbf    = (u16*)  (ws + 67108864);      //  8,388,608 B
    u16*   Wbf    = (u16*)  (ws + 75497472);      //  8,388,608 B
    u16*   WTbf   = (u16*)  (ws + 83886080);      //  8,388,608 B
    u16*   oWb    = (u16*)  (ws + 92274688);      // 65,536,000 B
    float* part_m = (float*)(ws + 157810688);     //  4,096,000 B
    float* part_s = (float*)(ws + 161906688);     //  4,096,000 B
    float* tlog   = (float*)(ws + 166002688);     //     16,384 B
    float* scal   = (float*)(ws + 166019072);     //        256 B

    hipMemsetAsync(scal, 0, 256, stream);
    gather_k<<<M_ROWS, 256, 0, stream>>>(ids, emb, xbf);
    conv_w_k<<<dim3(32, 32, 4), dim3(32, 32), 0, stream>>>(W, Wbf, WTbf);
    conv_outw_k<<<(V_DIM * D_DIM) / 1024, 256, 0, stream>>>(oW, oWb);
    init_states_k<<<(4 * (int)SM) / 1024, 256, 0, stream>>>(si, sbf);

    for (int step = 0; step < STEPS; ++step) {
        eps_gemm_k<<<dim3(8, 32, 4), 256, 0, stream>>>(sbf, Wbf, xbf, bs, epsb,
                                                       nullptr);
        upd_gemm_k<<<dim3(8, 32, 4), 256, 0, stream>>>(epsb, WTbf, sbf);
    }
    // final eps pass: no eps write, accumulate sum(eps^2) directly
    eps_gemm_k<<<dim3(8, 32, 4), 256, 0, stream>>>(sbf, Wbf, xbf, bs, epsb,
                                                   scal + 1);
    logits_k<<<dim3(32, V_DIM / 128), 256, 0, stream>>>(sbf + 3 * SM, oWb, ob, tgt,
                                                        part_m, part_s, tlog);
    ce_reduce_k<<<M_ROWS, 256, 0, stream>>>(part_m, part_s, tlog, scal);
    finalize_k<<<1, 1, 0, stream>>>(scal, (float*)d_out);
}

// Round 7
// 1567.951 us; speedup vs baseline: 1.4630x; 1.0333x over previous
//
#include <hip/hip_runtime.h>

typedef unsigned short u16;
typedef __attribute__((ext_vector_type(8))) __bf16 bf16x8;
typedef __attribute__((ext_vector_type(4))) float floatx4;

#define NUM_LAYERS 4
#define STEPS 8
#define LRS 0.1f
#define M_ROWS 4096            // B*S
#define D_DIM 1024
#define V_DIM 32000
#define KDIM 1024              // GEMM K (compile-time: strength-reduce addresses)
#define SM ((size_t)M_ROWS * D_DIM)      // elements per state buffer
#define WM ((size_t)D_DIM * D_DIM)       // elements per W

__device__ __forceinline__ u16 f2b(float f) {
    union { float f; unsigned u; } c; c.f = f;
    unsigned u = c.u;
    u = (u + 0x7FFFu + ((u >> 16) & 1u)) >> 16;   // RNE
    return (u16)u;
}
__device__ __forceinline__ float b2f(u16 b) {
    union { unsigned u; float f; } c; c.u = ((unsigned)b) << 16;
    return c.f;
}
__device__ __forceinline__ unsigned pk2(float a, float b) {
    return (unsigned)f2b(a) | ((unsigned)f2b(b) << 16);
}

// async 16B global -> LDS (wave-uniform LDS base + lane*16)
__device__ __forceinline__ void ld16(const u16* g, u16* l) {
    __builtin_amdgcn_global_load_lds(
        (const __attribute__((address_space(1))) void*)g,
        (__attribute__((address_space(3))) void*)l, 16, 0, 0);
}

// ---------------------------------------------------------------------------
// Shared GEMM core: C(128x128 f32 acc) = A(M x 1024 bf16, row-major)
//                                      @ B^T(N x 1024 bf16, row-major)
// 256 threads = 4 waves in 2x2; each wave 64x64 = 4x4 frags of 16x16x32 MFMA.
// BK=64 K-tile as TWO 32-col sub-tiles (verified conflict-free XOR-swizzled
// stride-32 layout each) -> halves barrier count vs BK=32.
// R6 LESSON: af[4]+bfv[4] arrays per half let the scheduler keep ~36 frag
// VGPRs live -> acc spilled under the launch_bounds(256,4) 128-reg cap
// (WRITE_SIZE 8->96MB). Here: bfv[4] per half + ONE A-fragment at a time
// (peak frag liveness ~22 VGPRs) so no spill at 4 blocks/CU.
// smem: caller-provided 16384 u16 (A halves [0,8192), B halves [8192,16384)).
// ---------------------------------------------------------------------------
__device__ __forceinline__ void gemm_core(const u16* __restrict__ A,
                                          const u16* __restrict__ B,
                                          int m0, int n0,
                                          floatx4 (&acc)[4][4],
                                          u16* smem) {
    u16* a_lds = smem;           // [2][4096] halves
    u16* b_lds = smem + 8192;
    const int tid  = threadIdx.x;
    const int lane = tid & 63;
    const int wave = tid >> 6;
    const int wm = wave >> 1, wn = wave & 1;
    const int q = lane >> 4, lr = lane & 15;
    const int qs = q ^ ((lr >> 1) & 3);          // read-side swizzle

    const int r0 = wave * 16 + (lane >> 2);
    const int cc = ((lane & 3) ^ ((lane >> 3) & 3)) * 8;
    const u16* ga = A + ((size_t)(m0 + r0) << 10) + cc;   // row stride 1024
    const u16* gb = B + ((size_t)(n0 + r0) << 10) + cc;
    u16* la = &a_lds[wave * 512];
    u16* lb = &b_lds[wave * 512];

    #pragma unroll
    for (int i = 0; i < 4; i++)
        #pragma unroll
        for (int j = 0; j < 4; j++)
            acc[i][j] = floatx4{0.f, 0.f, 0.f, 0.f};

    for (int kt = 0; kt < KDIM; kt += 64) {
        __syncthreads();                 // previous iter's LDS reads done
        ld16(ga + kt,                   la);
        ld16(ga + kt + 32,              la + 4096);
        ld16(ga + (64 << 10) + kt,      la + 2048);
        ld16(ga + (64 << 10) + kt + 32, la + 2048 + 4096);
        ld16(gb + kt,                   lb);
        ld16(gb + kt + 32,              lb + 4096);
        ld16(gb + (64 << 10) + kt,      lb + 2048);
        ld16(gb + (64 << 10) + kt + 32, lb + 2048 + 4096);
        __syncthreads();                 // drains vmcnt before reads
        #pragma unroll
        for (int h = 0; h < 2; h++) {
            bf16x8 bfv[4];
            #pragma unroll
            for (int ni = 0; ni < 4; ni++)
                bfv[ni] = *(const bf16x8*)
                    &b_lds[h * 4096 + (wn * 64 + ni * 16 + lr) * 32 + qs * 8];
            #pragma unroll
            for (int mi = 0; mi < 4; mi++) {
                bf16x8 a = *(const bf16x8*)
                    &a_lds[h * 4096 + (wm * 64 + mi * 16 + lr) * 32 + qs * 8];
                #pragma unroll
                for (int ni = 0; ni < 4; ni++)
                    acc[mi][ni] = __builtin_amdgcn_mfma_f32_16x16x32_bf16(
                        a, bfv[ni], acc[mi][ni], 0, 0, 0);
            }
        }
    }
}

// Epilogue staging map (32 rows x 128 cols bf16 per pass, 8KB in smem[0..4095]):
//   slot row  = wm*16 + q*4 + r  (global row = m0 + (row>>4)*64 + mi*16 + (row&15))
//   col chunk rotation: slot_chunk = (chunk + 4*((row>>2)&3)) & 15  -> both LDS
//   phases uniform 2-way bank touches (free).

// eps_l = lower - b - mu_l @ W^T. If pc_accum==null: write eps as bf16 (16B
// coalesced). Else: skip the write, accumulate sum(eps^2) into *pc_accum.
__global__ __launch_bounds__(256, 4) void eps_gemm_k(
        const u16* __restrict__ sbf, const u16* __restrict__ Wbf,
        const u16* __restrict__ xbf, const float* __restrict__ b_stack,
        u16* __restrict__ epsb, float* __restrict__ pc_accum) {
    __shared__ __align__(16) u16 smem[16384];
    const int z = blockIdx.z;
    const int m0 = blockIdx.y * 128, n0 = blockIdx.x * 128;
    floatx4 acc[4][4];
    gemm_core(sbf + (size_t)z * SM, Wbf + (size_t)z * WM, m0, n0, acc, smem);
    const u16* lower = (z == 0) ? xbf : (sbf + (size_t)(z - 1) * SM);
    const float* bias = b_stack + z * D_DIM;
    u16* eo = epsb + (size_t)z * SM;
    const int tid = threadIdx.x, lane = tid & 63, wave = tid >> 6;
    const int wm = wave >> 1, wn = wave & 1, q = lane >> 4, lr = lane & 15;
    float sq = 0.f;
    #pragma unroll
    for (int mi = 0; mi < 4; mi++) {
        __syncthreads();
        #pragma unroll
        for (int ni = 0; ni < 4; ni++) {
            const int col = wn * 64 + ni * 16 + lr;
            const float bc = bias[n0 + col];
            #pragma unroll
            for (int r = 0; r < 4; r++) {
                const int row = wm * 16 + q * 4 + r;
                const int scn = ((col >> 3) + ((row >> 2) & 3) * 4) & 15;
                smem[row * 128 + scn * 8 + (col & 7)] = f2b(acc[mi][ni][r] + bc);
            }
        }
        __syncthreads();
        #pragma unroll
        for (int h = 0; h < 2; h++) {
            const int c = tid + h * 256;
            const int lrow = c >> 4, ch = c & 15;
            const int scn = (ch + ((lrow >> 2) & 3) * 4) & 15;
            const int grow = m0 + (lrow >> 4) * 64 + mi * 16 + (lrow & 15);
            const size_t gidx = (size_t)grow * D_DIM + n0 + ch * 8;
            bf16x8 st = *(const bf16x8*)&smem[lrow * 128 + scn * 8];
            bf16x8 lo = *(const bf16x8*)(lower + gidx);
            float e[8];
            #pragma unroll
            for (int i = 0; i < 8; i++) e[i] = (float)lo[i] - (float)st[i];
            if (pc_accum) {
                #pragma unroll
                for (int i = 0; i < 8; i++) sq += e[i] * e[i];
            } else {
                uint4 ov;
                ov.x = pk2(e[0], e[1]); ov.y = pk2(e[2], e[3]);
                ov.z = pk2(e[4], e[5]); ov.w = pk2(e[6], e[7]);
                *(uint4*)(eo + gidx) = ov;
            }
        }
    }
    if (pc_accum) {
        #pragma unroll
        for (int off = 1; off < 64; off <<= 1) sq += __shfl_xor(sq, off, 64);
        __shared__ float ls[4];
        if (lane == 0) ls[wave] = sq;
        __syncthreads();
        if (tid == 0) atomicAdd(pc_accum, ls[0] + ls[1] + ls[2] + ls[3]);
    }
}

// s_l += LR*(eps_l @ W) - LR*eps_{l+1};  states live as bf16 only
__global__ __launch_bounds__(256, 4) void upd_gemm_k(
        const u16* __restrict__ epsb, const u16* __restrict__ WTbf,
        u16* __restrict__ sbf) {
    __shared__ __align__(16) u16 smem[16384];
    const int z = blockIdx.z;
    const int m0 = blockIdx.y * 128, n0 = blockIdx.x * 128;
    floatx4 acc[4][4];
    gemm_core(epsb + (size_t)z * SM, WTbf + (size_t)z * WM, m0, n0, acc, smem);
    u16* Sb = sbf + (size_t)z * SM;
    const bool hn = (z < 3);
    const u16* en = epsb + (size_t)(hn ? (z + 1) : z) * SM;
    const int tid = threadIdx.x, lane = tid & 63, wave = tid >> 6;
    const int wm = wave >> 1, wn = wave & 1, q = lane >> 4, lr = lane & 15;
    #pragma unroll
    for (int mi = 0; mi < 4; mi++) {
        __syncthreads();
        #pragma unroll
        for (int ni = 0; ni < 4; ni++) {
            const int col = wn * 64 + ni * 16 + lr;
            #pragma unroll
            for (int r = 0; r < 4; r++) {
                const int row = wm * 16 + q * 4 + r;
                const int scn = ((col >> 3) + ((row >> 2) & 3) * 4) & 15;
                smem[row * 128 + scn * 8 + (col & 7)] = f2b(LRS * acc[mi][ni][r]);
            }
        }
        __syncthreads();
        #pragma unroll
        for (int h = 0; h < 2; h++) {
            const int c = tid + h * 256;
            const int lrow = c >> 4, ch = c & 15;
            const int scn = (ch + ((lrow >> 2) & 3) * 4) & 15;
            const int grow = m0 + (lrow >> 4) * 64 + mi * 16 + (lrow & 15);
            const size_t gidx = (size_t)grow * D_DIM + n0 + ch * 8;
            bf16x8 st = *(const bf16x8*)&smem[lrow * 128 + scn * 8];
            bf16x8 S8 = *(const bf16x8*)(Sb + gidx);
            float v[8];
            #pragma unroll
            for (int i = 0; i < 8; i++) v[i] = (float)S8[i] + (float)st[i];
            if (hn) {
                bf16x8 e8 = *(const bf16x8*)(en + gidx);
                #pragma unroll
                for (int i = 0; i < 8; i++) v[i] -= LRS * (float)e8[i];
            }
            uint4 ov;
            ov.x = pk2(v[0], v[1]); ov.y = pk2(v[2], v[3]);
            ov.z = pk2(v[4], v[5]); ov.w = pk2(v[6], v[7]);
            *(uint4*)(Sb + gidx) = ov;
        }
    }
}

// logits tile + fused online-softmax partials + target-logit capture
// grid: x = m-tile (32, fastest) so co-resident blocks share one B n-strip
__global__ __launch_bounds__(256, 4) void logits_k(
        const u16* __restrict__ s4bf, const u16* __restrict__ oWb,
        const float* __restrict__ out_b, const int* __restrict__ targets,
        float* __restrict__ part_m, float* __restrict__ part_s,
        float* __restrict__ tlog) {
    __shared__ __align__(16) u16 smem[16384];
    const int m0 = blockIdx.x * 128, n0 = blockIdx.y * 128;
    floatx4 acc[4][4];
    gemm_core(s4bf, oWb, m0, n0, acc, smem);
    __shared__ float redm[128][2];
    __shared__ float reds[128][2];
    const int tid = threadIdx.x, lane = tid & 63, wave = tid >> 6;
    const int wm = wave >> 1, wn = wave & 1, q = lane >> 4, lr = lane & 15;
    float ob[4];
    #pragma unroll
    for (int ni = 0; ni < 4; ni++) ob[ni] = out_b[n0 + wn * 64 + ni * 16 + lr];
    #pragma unroll
    for (int mi = 0; mi < 4; mi++) {
        #pragma unroll
        for (int r = 0; r < 4; r++) {
            const int grow = m0 + wm * 64 + mi * 16 + q * 4 + r;
            float l[4];
            #pragma unroll
            for (int ni = 0; ni < 4; ni++) l[ni] = acc[mi][ni][r] + ob[ni];
            if ((grow & 511) != 511) {           // valid row (s < 511)
                const int t = targets[grow + 1];
                #pragma unroll
                for (int ni = 0; ni < 4; ni++) {
                    const int gcol = n0 + wn * 64 + ni * 16 + lr;
                    if (t == gcol) tlog[grow] = l[ni];
                }
            }
            float mx = fmaxf(fmaxf(l[0], l[1]), fmaxf(l[2], l[3]));
            #pragma unroll
            for (int off = 1; off < 16; off <<= 1)
                mx = fmaxf(mx, __shfl_xor(mx, off, 64));
            float sm = __expf(l[0] - mx) + __expf(l[1] - mx) +
                       __expf(l[2] - mx) + __expf(l[3] - mx);
            #pragma unroll
            for (int off = 1; off < 16; off <<= 1)
                sm += __shfl_xor(sm, off, 64);
            if (lr == 0) {
                const int rrow = wm * 64 + mi * 16 + q * 4 + r;
                redm[rrow][wn] = mx;
                reds[rrow][wn] = sm;
            }
        }
    }
    __syncthreads();
    if (tid < 128) {
        float ma = redm[tid][0], mb = redm[tid][1];
        float M = fmaxf(ma, mb);
        float S = reds[tid][0] * __expf(ma - M) + reds[tid][1] * __expf(mb - M);
        part_m[(size_t)blockIdx.y * M_ROWS + m0 + tid] = M;
        part_s[(size_t)blockIdx.y * M_ROWS + m0 + tid] = S;
    }
}

__global__ void gather_k(const int* __restrict__ ids,
                         const float* __restrict__ emb,
                         u16* __restrict__ xbf) {
    const int row = blockIdx.x;
    const int c = threadIdx.x * 4;
    float4 v = *(const float4*)(emb + (size_t)ids[row] * D_DIM + c);
    uint2 o; o.x = pk2(v.x, v.y); o.y = pk2(v.z, v.w);
    *(uint2*)(xbf + (size_t)row * D_DIM + c) = o;
}

__global__ void conv_w_k(const float* __restrict__ W,
                         u16* __restrict__ Wbf, u16* __restrict__ WTbf) {
    __shared__ float t[32][33];
    const int z = blockIdx.z;
    const int i = blockIdx.y * 32 + threadIdx.y;
    const int j = blockIdx.x * 32 + threadIdx.x;
    const float v = W[(size_t)z * WM + (size_t)i * D_DIM + j];
    Wbf[(size_t)z * WM + (size_t)i * D_DIM + j] = f2b(v);
    t[threadIdx.y][threadIdx.x] = v;
    __syncthreads();
    const int jo = blockIdx.x * 32 + threadIdx.y;
    const int io = blockIdx.y * 32 + threadIdx.x;
    WTbf[(size_t)z * WM + (size_t)jo * D_DIM + io] = f2b(t[threadIdx.x][threadIdx.y]);
}

__global__ void conv_outw_k(const float* __restrict__ oW, u16* __restrict__ oWb) {
    const size_t i = ((size_t)blockIdx.x * 256 + threadIdx.x) * 4;
    float4 v = *(const float4*)(oW + i);
    uint2 o; o.x = pk2(v.x, v.y); o.y = pk2(v.z, v.w);
    *(uint2*)(oWb + i) = o;
}

__global__ void init_states_k(const float* __restrict__ si,
                              u16* __restrict__ sbf) {
    const size_t i = ((size_t)blockIdx.x * 256 + threadIdx.x) * 4;
    float4 v = *(const float4*)(si + i);
    uint2 o; o.x = pk2(v.x, v.y); o.y = pk2(v.z, v.w);
    *(uint2*)(sbf + i) = o;
}

__global__ void ce_reduce_k(const float* __restrict__ part_m,
                            const float* __restrict__ part_s,
                            const float* __restrict__ tlog,
                            float* __restrict__ ce_sum) {
    const int row = blockIdx.x;
    if ((row & 511) == 511) return;
    const int tid = threadIdx.x;
    const int NT = V_DIM / 128;  // 250
    float m = -3.0e38f;
    for (int nt = tid; nt < NT; nt += 256)
        m = fmaxf(m, part_m[(size_t)nt * M_ROWS + row]);
    #pragma unroll
    for (int off = 1; off < 64; off <<= 1) m = fmaxf(m, __shfl_xor(m, off, 64));
    __shared__ float sm[4], ss[4];
    if ((tid & 63) == 0) sm[tid >> 6] = m;
    __syncthreads();
    m = fmaxf(fmaxf(sm[0], sm[1]), fmaxf(sm[2], sm[3]));
    float s = 0.f;
    for (int nt = tid; nt < NT; nt += 256)
        s += part_s[(size_t)nt * M_ROWS + row] *
             __expf(part_m[(size_t)nt * M_ROWS + row] - m);
    #pragma unroll
    for (int off = 1; off < 64; off <<= 1) s += __shfl_xor(s, off, 64);
    if ((tid & 63) == 0) ss[tid >> 6] = s;
    __syncthreads();
    if (tid == 0) {
        float loss = m + __logf(ss[0] + ss[1] + ss[2] + ss[3]) - tlog[row];
        atomicAdd(ce_sum, loss);
    }
}

__global__ void finalize_k(const float* __restrict__ scal, float* __restrict__ out) {
    out[0] = scal[0] / 4088.0f;
    out[1] = scal[1] / (float)(4 * SM);
}

extern "C" void kernel_launch(void* const* d_in, const int* in_sizes, int n_in,
                              void* d_out, int out_size, void* d_ws, size_t ws_size,
                              hipStream_t stream) {
    (void)in_sizes; (void)n_in; (void)out_size; (void)ws_size;
    const int*   ids = (const int*)d_in[0];
    const int*   tgt = (const int*)d_in[1];
    const float* emb = (const float*)d_in[2];
    const float* W   = (const float*)d_in[3];
    const float* bs  = (const float*)d_in[4];
    const float* oW  = (const float*)d_in[5];
    const float* ob  = (const float*)d_in[6];
    const float* si  = (const float*)d_in[7];

    char* ws = (char*)d_ws;
    u16*   sbf    = (u16*)  (ws + 0);             // 33,554,432 B
    u16*   epsb   = (u16*)  (ws + 33554432);      // 33,554,432 B
    u16*   xbf    = (u16*)  (ws + 67108864);      //  8,388,608 B
    u16*   Wbf    = (u16*)  (ws + 75497472);      //  8,388,608 B
    u16*   WTbf   = (u16*)  (ws + 83886080);      //  8,388,608 B
    u16*   oWb    = (u16*)  (ws + 92274688);      // 65,536,000 B
    float* part_m = (float*)(ws + 157810688);     //  4,096,000 B
    float* part_s = (float*)(ws + 161906688);     //  4,096,000 B
    float* tlog   = (float*)(ws + 166002688);     //     16,384 B
    float* scal   = (float*)(ws + 166019072);     //        256 B

    hipMemsetAsync(scal, 0, 256, stream);
    gather_k<<<M_ROWS, 256, 0, stream>>>(ids, emb, xbf);
    conv_w_k<<<dim3(32, 32, 4), dim3(32, 32), 0, stream>>>(W, Wbf, WTbf);
    conv_outw_k<<<(V_DIM * D_DIM) / 1024, 256, 0, stream>>>(oW, oWb);
    init_states_k<<<(4 * (int)SM) / 1024, 256, 0, stream>>>(si, sbf);

    for (int step = 0; step < STEPS; ++step) {
        eps_gemm_k<<<dim3(8, 32, 4), 256, 0, stream>>>(sbf, Wbf, xbf, bs, epsb,
                                                       nullptr);
        upd_gemm_k<<<dim3(8, 32, 4), 256, 0, stream>>>(epsb, WTbf, sbf);
    }
    // final eps pass: no eps write, accumulate sum(eps^2) directly
    eps_gemm_k<<<dim3(8, 32, 4), 256, 0, stream>>>(sbf, Wbf, xbf, bs, epsb,
                                                   scal + 1);
    logits_k<<<dim3(32, V_DIM / 128), 256, 0, stream>>>(sbf + 3 * SM, oWb, ob, tgt,
                                                        part_m, part_s, tlog);
    ce_reduce_k<<<M_ROWS, 256, 0, stream>>>(part_m, part_s, tlog, scal);
    finalize_k<<<1, 1, 0, stream>>>(scal, (float*)d_out);
}